// Round 1
// 46.002 us; speedup vs baseline: 1.0598x; 1.0598x over previous
//
#include <hip/hip_runtime.h>
#include <hip/hip_fp16.h>
#include <math.h>

#define N_ATOMS 2048
#define NSP 7
#define AEVD 112      // real radial features; padded to 128 (K-tile) only in LDS
#define MTILE 16      // atoms per MLP block (full 16-row M-tile)
#define NBLK_MLP 135  // max tiles: 2048/16 + 7 slack
#define AEV_TASKS (N_ATOMS * NSP)           // (atom, species) wave-tasks, 16 shells each
#define AEV_BLKS (AEV_TASKS / 4)            // 3584 blocks of 4 waves

typedef __attribute__((ext_vector_type(8))) short short8;
typedef __attribute__((ext_vector_type(4))) float f32x4;
typedef unsigned short ushort_t;

// ---- guaranteed-native transcendentals (single HW instruction) ----
#if !__has_builtin(__builtin_amdgcn_exp2f)
extern "C" __device__ float __ocml_native_exp2_f32(float);
#endif
#if !__has_builtin(__builtin_amdgcn_cosf)
extern "C" __device__ float __ocml_native_cos_f32(float);
#endif
#if !__has_builtin(__builtin_amdgcn_sqrtf)
extern "C" __device__ float __ocml_native_sqrt_f32(float);
#endif

__device__ __forceinline__ float nexp2(float x) {       // 2^x  (v_exp_f32)
#if __has_builtin(__builtin_amdgcn_exp2f)
    return __builtin_amdgcn_exp2f(x);
#else
    return __ocml_native_exp2_f32(x);
#endif
}
__device__ __forceinline__ float ncos_rev(float x) {    // cos(2*pi*x) (v_cos_f32)
#if __has_builtin(__builtin_amdgcn_cosf)
    return __builtin_amdgcn_cosf(x);
#else
    return __ocml_native_cos_f32(x * 6.2831853071795865f);
#endif
}
__device__ __forceinline__ float nsqrt(float x) {       // sqrt(x) (v_sqrt_f32)
#if __has_builtin(__builtin_amdgcn_sqrtf)
    return __builtin_amdgcn_sqrtf(x);
#else
    return __ocml_native_sqrt_f32(x);
#endif
}

__device__ __constant__ float c_shfr[16] = {
    0.9f, 1.16f, 1.43f, 1.69f, 1.96f, 2.22f, 2.49f, 2.75f,
    3.02f, 3.28f, 3.55f, 3.81f, 4.08f, 4.34f, 4.61f, 4.87f};

#define CS_LOG2E  (-23.083120654223414f)   // -16*log2(e)
#define CB_LOG2E  ( 46.166241308446828f)   // +32*log2(e)
#define EA_COEF   ( 12.003222740196175f)   // CB_LOG2E * 0.26 (even->odd shell step)

__device__ __forceinline__ float celu01(float x) {
    return x > 0.f ? x : 0.1f * (nexp2(x * 14.426950f) - 1.f);
}

__device__ __forceinline__ ushort_t f2bf(float v) {   // RNE fp32->bf16
    unsigned u = __float_as_uint(v);
    u += 0x7fffu + ((u >> 16) & 1u);
    return (ushort_t)(u >> 16);
}

// ---------------------------------------------------------------------------
// Kernel 1 (fused): block 0 = deterministic counting sort (seg + cxyz +
// counter=0); blocks 1..385 = weight repack fp32->bf16 (overlaps the sort).
// ---------------------------------------------------------------------------
#define PREP_G0 28672   // 7*16*4*64
#define PREP_G1 43008   // 7*12*8*64
#define PREP_G2 26880   // 7*10*6*64
#define PREP_GT (PREP_G0 + PREP_G1 + PREP_G2)   // 98560 = 385*256

__global__ __launch_bounds__(256) void sortprep_kernel(
    const int* __restrict__ species, const float* __restrict__ coords,
    int* __restrict__ seg, float4* __restrict__ cxyz,
    unsigned* __restrict__ counter,
    const float* __restrict__ W0, const float* __restrict__ W1,
    const float* __restrict__ W2,
    ushort_t* __restrict__ wr0, ushort_t* __restrict__ wr1,
    ushort_t* __restrict__ wr2)
{
    __shared__ int cnt[256][NSP];
    __shared__ int wsum[4][NSP];
    __shared__ int sortedL[N_ATOMS];
    int t = threadIdx.x;

    if (blockIdx.x != 0) {
        int g = (blockIdx.x - 1) * 256 + t;
        if (g < PREP_GT) {
            const float* W; ushort_t* dst; int NT, KS, KREAL, KIN, NOUT;
            if (g < PREP_G0)                 { W = W0; dst = wr0; NT = 16; KS = 4; KREAL = 112; KIN = 1008; NOUT = 256; }
            else if (g < PREP_G0 + PREP_G1)  { g -= PREP_G0; W = W1; dst = wr1; NT = 12; KS = 8; KREAL = 256; KIN = 256; NOUT = 192; }
            else                             { g -= PREP_G0 + PREP_G1; W = W2; dst = wr2; NT = 10; KS = 6; KREAL = 192; KIN = 192; NOUT = 160; }
            int L = g & 63, rest = g >> 6;
            int ks = rest % KS; rest /= KS;
            int nt = rest % NT; int s = rest / NT;
            int n = nt * 16 + (L & 15);
            int k0 = ks * 32 + ((L >> 4) << 3);
            const float* src = W + (size_t)s * KIN * NOUT + n;
            short8 v8;
#pragma unroll
            for (int j = 0; j < 8; ++j) {
                int k = k0 + j;
                float v = (k < KREAL) ? src[(size_t)k * NOUT] : 0.f;
                v8[j] = (short)f2bf(v);
            }
            *(short8*)(dst + (size_t)g * 8) = v8;
        }
        return;
    }

    // ---- block 0: counting sort ----
    int lane = t & 63, wv = t >> 6;
    if (t == 0) counter[0] = 0u;

    int c[NSP];
#pragma unroll
    for (int s = 0; s < NSP; ++s) c[s] = 0;
    int spl[8];
#pragma unroll
    for (int i = 0; i < 8; ++i) {
        int s = species[t * 8 + i];
        spl[i] = s;
#pragma unroll
        for (int q = 0; q < NSP; ++q) c[q] += (s == q) ? 1 : 0;
    }
    int incl[NSP];
#pragma unroll
    for (int s = 0; s < NSP; ++s) {
        int v = c[s];
        for (int d = 1; d < 64; d <<= 1) {
            int o = __shfl_up(v, d);
            if (lane >= d) v += o;
        }
        incl[s] = v;
        if (lane == 63) wsum[wv][s] = v;
    }
    __syncthreads();

    int bs[NSP];
    int run = 0;
#pragma unroll
    for (int s = 0; s < NSP; ++s) {
        int w0 = wsum[0][s], w1 = wsum[1][s], w2 = wsum[2][s], w3 = wsum[3][s];
        int woff = (wv > 0 ? w0 : 0) + (wv > 1 ? w1 : 0) + (wv > 2 ? w2 : 0);
        int tot = w0 + w1 + w2 + w3;
        bs[s] = run + woff + incl[s] - c[s];
        if (t == 0) seg[s] = run;
        run += tot;
    }
    if (t == 0) seg[NSP] = run;

#pragma unroll
    for (int s = 0; s < NSP; ++s) cnt[t][s] = bs[s];
#pragma unroll
    for (int i = 0; i < 8; ++i) {
        int s = spl[i];
        int pos = cnt[t][s]++;
        sortedL[pos] = t * 8 + i;
    }
    __syncthreads();

    for (int p = t; p < N_ATOMS; p += 256) {
        int j = sortedL[p];
        cxyz[p] = make_float4(coords[3 * j + 0], coords[3 * j + 1],
                              coords[3 * j + 2], 0.f);
    }
}

// ---------------------------------------------------------------------------
// Kernel 2: radial AEV, one wave-task = (atom, species), all 16 shells.
// R1: even shells direct (8 exps), odd shells derived via the exact
// alternating-grid identity  v_odd = v_even * exp2(12.0032*d) * CK  (the
// SHFR grid steps even->odd by exactly 0.26).  d clamped to 5.2 for shell
// math: fc(5.2)=0 makes the clamp exact and keeps exp2(12*d) finite.
// Reduction: 16 fp32 accs packed to 8 half2, butterfly with v_pk_add_f16.
// ---------------------------------------------------------------------------
__global__ __launch_bounds__(256) void aev_kernel(
    const int* __restrict__ seg, const float4* __restrict__ cxyz,
    ushort_t* __restrict__ aevb)
{
    int t = threadIdx.x;
    int jl = t & 63;
    int gid = blockIdx.x * 4 + (t >> 6);   // 0 .. 14335
    int atom = gid / 7;                    // magic-mul const div
    int s = gid - atom * 7;

    float4 ci = cxyz[atom];
    float xi = ci.x, yi = ci.y, zi = ci.z;
    int pb = seg[s], pe = seg[s + 1];

    float BE[8], GE[8], CK[8];
#pragma unroll
    for (int j = 0; j < 8; ++j) {
        float me = c_shfr[2 * j], mo = c_shfr[2 * j + 1];
        BE[j] = CB_LOG2E * me;
        GE[j] = CS_LOG2E * (me * me);
        CK[j] = nexp2(CS_LOG2E * (mo * mo - me * me));   // 2^{CS*(mu_o^2-mu_e^2)}
    }

    float acc[16];
#pragma unroll
    for (int k = 0; k < 16; ++k) acc[k] = 0.f;

    for (int p = pb + jl; p < pe; p += 64) {
        float4 cj = cxyz[p];                       // L1-resident (32KB total)
        float dx = cj.x - xi, dy = cj.y - yi, dz = cj.z - zi;
        float sq = fmaf(dx, dx, fmaf(dy, dy, dz * dz));
        float d  = nsqrt(sq);
        float dc = fminf(d, 5.2f);                 // clamp: exact for fc!=0 pairs
        float fcv = fmaf(0.5f, ncos_rev(dc * 0.09615384615f), 0.5f);  // 0 at dc=5.2
        float fc = (sq > 0.f) ? fcv : 0.f;         // mask self only
        float uc = CS_LOG2E * (dc * dc);
        float ea = nexp2(dc * EA_COEF);            // shared even->odd ratio
        float fe = ea * fc;
#pragma unroll
        for (int j = 0; j < 8; ++j) {
            float ve = nexp2(fmaf(dc, BE[j], uc) + GE[j]);   // even shell, exact
            acc[2 * j]     = fmaf(ve, fc, acc[2 * j]);
            acc[2 * j + 1] = fmaf(ve * fe, CK[j], acc[2 * j + 1]);  // odd shell
        }
    }

    // ---- packed-f16 butterfly reduction (halves shfl+add count) ----
    __half2 h[8];
#pragma unroll
    for (int j = 0; j < 8; ++j)
        h[j] = __floats2half2_rn(acc[2 * j], acc[2 * j + 1]);
#pragma unroll
    for (int off = 32; off > 0; off >>= 1) {
#pragma unroll
        for (int j = 0; j < 8; ++j) {
            unsigned u;
            __builtin_memcpy(&u, &h[j], 4);
            unsigned o = __shfl_down(u, off);
            __half2 oh;
            __builtin_memcpy(&oh, &o, 4);
            h[j] = __hadd2(h[j], oh);              // v_pk_add_f16
        }
    }
    if (jl == 0) {
        short8 lo, hi;
#pragma unroll
        for (int j = 0; j < 8; ++j) {
            float2 f = __half22float2(h[j]);
            int k = 2 * j;
            if (k < 8) {
                lo[k] = (short)f2bf(f.x);
                lo[k + 1] = (short)f2bf(f.y);
            } else {
                hi[k - 8] = (short)f2bf(f.x);
                hi[k - 7] = (short)f2bf(f.y);
            }
        }
        ushort_t* dstp = aevb + (size_t)atom * AEVD + s * 16;
        *(short8*)(dstp) = lo;
        *(short8*)(dstp + 8) = hi;
    }
}

// ---------------------------------------------------------------------------
// Kernel 3: MFMA MLP — 512 threads, 8 waves split the N-tiles (max 2
// tiles/wave), weights loaded PER LAYER just before use: max live weight
// state 16 short8 = 64 VGPR (was 232 hoisted -> spills). 2 waves/SIMD.
// ---------------------------------------------------------------------------

template<int KSTEPS, int NT, int SIN, int NOUT, bool OUTF32>
__device__ __forceinline__ void compute_layer8(
    const ushort_t* __restrict__ wrep,   // this species' fragment-linear base
    const float* __restrict__ bias,
    const ushort_t* Ain,                 // LDS bf16 [16][SIN], swizzled
    ushort_t* Aout,                      // LDS bf16 [16][NOUT], swizzled
    float* Fout,                         // LDS fp32 [16][NOUT] (if OUTF32)
    int lane, int wv)
{
    constexpr int MAXNT = (NT + 7) / 8;
    const int myNT = (NT - wv + 7) / 8;

    // B fragments for THIS layer only (issued first; latency overlaps af reads)
    short8 wf[MAXNT][KSTEPS];
#pragma unroll
    for (int i = 0; i < MAXNT; ++i) {
        if (i < myNT) {
            int nt = wv + i * 8;
            const ushort_t* wb = wrep + ((size_t)nt * KSTEPS) * 512 + lane * 8;
#pragma unroll
            for (int ks = 0; ks < KSTEPS; ++ks)
                wf[i][ks] = *(const short8*)(wb + ks * 512);
        }
    }
    // A fragments (shared across this wave's N-tiles)
    short8 af[KSTEPS];
    {
        int m = lane & 15;
        int kb = (lane >> 4) << 3;
        unsigned base = (unsigned)(m * (SIN * 2));
        unsigned swz = (unsigned)((m & 7) << 4);
#pragma unroll
        for (int ks = 0; ks < KSTEPS; ++ks) {
            unsigned addr = (base + (unsigned)((ks * 32 + kb) * 2)) ^ swz;
            af[ks] = *(const short8*)((const char*)Ain + addr);
        }
    }
    f32x4 acc[MAXNT];
#pragma unroll
    for (int i = 0; i < MAXNT; ++i) {
        acc[i] = (f32x4){0.f, 0.f, 0.f, 0.f};
        if (i < myNT) {
#pragma unroll
            for (int ks = 0; ks < KSTEPS; ++ks)
                acc[i] = __builtin_amdgcn_mfma_f32_16x16x32_bf16(af[ks], wf[i][ks], acc[i], 0, 0, 0);
        }
    }
    // epilogue: bias + celu; D layout: n = lane&15, m = (lane>>4)*4 + r
#pragma unroll
    for (int i = 0; i < MAXNT; ++i) {
        if (i < myNT) {
            int nt = wv + i * 8;
            int n = nt * 16 + (lane & 15);
            float bb = bias[n];
#pragma unroll
            for (int r = 0; r < 4; ++r) {
                int m = ((lane >> 4) << 2) + r;
                float v = celu01(acc[i][r] + bb);
                if (OUTF32) {
                    Fout[m * NOUT + n] = v;
                } else {
                    unsigned addr = (unsigned)(m * (NOUT * 2) + n * 2) ^ ((unsigned)((m & 7) << 4));
                    *(ushort_t*)((char*)Aout + addr) = f2bf(v);
                }
            }
        }
    }
    __syncthreads();
}

__global__ __launch_bounds__(512, 1) void mlp_kernel(
    const int* __restrict__ seg, const ushort_t* __restrict__ aevb,
    const ushort_t* __restrict__ wr0, const ushort_t* __restrict__ wr1,
    const ushort_t* __restrict__ wr2,
    const float* __restrict__ b0, const float* __restrict__ b1,
    const float* __restrict__ b2,
    const float* __restrict__ W3, const float* __restrict__ b3,
    float* __restrict__ ebuf, unsigned* __restrict__ counter,
    float* __restrict__ out)
{
    __shared__ __align__(16) ushort_t bufA[16 * 256];
    __shared__ __align__(16) ushort_t bufB[16 * 256];
    __shared__ __align__(16) float h2f[16 * 160];
    __shared__ float ered[MTILE];

    int t = threadIdx.x;
    int lane = t & 63, wv = t >> 6;
    int bid = blockIdx.x;

    int sfound = -1, tile = 0, segbase = 0, na = 0;
    int t0 = 0;
    for (int s = 0; s < NSP; ++s) {
        int beg = seg[s], end = seg[s + 1];
        int n = end - beg;
        int nt = (n + MTILE - 1) >> 4;
        if (sfound < 0 && bid < t0 + nt) {
            sfound = s; tile = bid - t0; segbase = beg;
            int rem = n - tile * MTILE;
            na = rem < MTILE ? rem : MTILE;
        }
        t0 += nt;
    }

    float ssum = 0.f;
    if (sfound >= 0) {
        int s = sfound;
        int row0 = segbase + tile * MTILE;

        float w3v[5];
        {
            const float* w3 = W3 + (size_t)s * 160 + (t & 31);
#pragma unroll
            for (int j = 0; j < 5; ++j) w3v[j] = w3[j * 32];
        }

        // stage AEV rows (bf16, swizzled); rows>=na, cols>=112 zeroed
        if (t < 256) {
            int m = t >> 4, piece = t & 15;
            short8 v = (short8){0,0,0,0,0,0,0,0};
            if (m < na && piece < 14)
                v = *(const short8*)(aevb + (size_t)(row0 + m) * AEVD + piece * 8);
            unsigned addr = (unsigned)(m * 256 + piece * 16) ^ ((unsigned)((m & 7) << 4));
            *(short8*)((char*)bufA + addr) = v;
        }
        __syncthreads();

        compute_layer8<4, 16, 128, 256, false>(wr0 + (size_t)s * 16 * 4 * 512, b0 + s * 256,
                                               bufA, bufB, nullptr, lane, wv);
        compute_layer8<8, 12, 256, 192, false>(wr1 + (size_t)s * 12 * 8 * 512, b1 + s * 192,
                                               bufB, bufA, nullptr, lane, wv);
        compute_layer8<6, 10, 192, 160, true >(wr2 + (size_t)s * 10 * 6 * 512, b2 + s * 160,
                                               bufA, nullptr, h2f, lane, wv);

        // ---- Layer 3: 160 -> 1 per atom (32 lanes per atom, 16 atoms) ----
        {
            int a = t >> 5, l = t & 31;
            float part = 0.f;
#pragma unroll
            for (int j = 0; j < 5; ++j) part = fmaf(h2f[a * 160 + l + j * 32], w3v[j], part);
            for (int off = 16; off; off >>= 1) part += __shfl_down(part, off, 32);
            if (l == 0) ered[a] = part;
        }
        __syncthreads();
        if (t == 0) {
            for (int a = 0; a < na; ++a) ssum += ered[a] + b3[s];
        }
    }

    // completion protocol: last block reduces ebuf in FIXED order (deterministic)
    if (t == 0) {
        ebuf[bid] = ssum;
        __threadfence();
        unsigned old = atomicAdd(counter, 1u);
        if (old == (unsigned)gridDim.x - 1u) {
            __threadfence();
            float tot = 0.f;
            for (int i = 0; i < (int)gridDim.x; ++i) tot += ebuf[i];
            out[0] = tot;
        }
    }
}

extern "C" void kernel_launch(void* const* d_in, const int* in_sizes, int n_in,
                              void* d_out, int out_size, void* d_ws, size_t ws_size,
                              hipStream_t stream)
{
    const int*   species = (const int*)d_in[0];
    const float* coords  = (const float*)d_in[1];
    const float* W0 = (const float*)d_in[2];
    const float* b0 = (const float*)d_in[3];
    const float* W1 = (const float*)d_in[4];
    const float* b1 = (const float*)d_in[5];
    const float* W2 = (const float*)d_in[6];
    const float* b2 = (const float*)d_in[7];
    const float* W3 = (const float*)d_in[8];
    const float* b3 = (const float*)d_in[9];
    float* out = (float*)d_out;

    // Workspace layout: total 2,069,632 B (< 2 MiB)
    char* ws = (char*)d_ws;
    int*      seg     = (int*)(ws);                   // [0, 32)
    unsigned* counter = (unsigned*)(ws + 48);         // [48, 52)
    float*    ebuf    = (float*)(ws + 64);            // 135 f32
    float4*   cxyz    = (float4*)(ws + 1152);         // 2048 float4 (32 KB)
    ushort_t* aevb    = (ushort_t*)(ws + 33920);      // 2048*112 bf16 (448 KB)
    ushort_t* wr0     = (ushort_t*)(ws + 492672);     // 229376 bf16
    ushort_t* wr1     = (ushort_t*)(ws + 951424);     // 344064 bf16
    ushort_t* wr2     = (ushort_t*)(ws + 1639552);    // 215040 bf16

    hipLaunchKernelGGL(sortprep_kernel, dim3(386), dim3(256), 0, stream,
                       species, coords, seg, cxyz, counter,
                       W0, W1, W2, wr0, wr1, wr2);
    hipLaunchKernelGGL(aev_kernel, dim3(AEV_BLKS), dim3(256), 0, stream,
                       seg, cxyz, aevb);
    hipLaunchKernelGGL(mlp_kernel, dim3(NBLK_MLP), dim3(512), 0, stream,
                       seg, aevb, wr0, wr1, wr2, b0, b1, b2, W3, b3,
                       ebuf, counter, out);
}

// Round 3
// 44.570 us; speedup vs baseline: 1.0938x; 1.0321x over previous
//
#include <hip/hip_runtime.h>
#include <hip/hip_fp16.h>
#include <math.h>

#define N_ATOMS 2048
#define NSP 7
#define AEVD 112      // real radial features; padded to 128 (K-tile) only in LDS
#define MTILE 16      // atoms per MLP block (full 16-row M-tile)
#define NBLK_MLP 135  // max tiles: 2048/16 + 7 slack
#define AEV_TASKS (N_ATOMS * NSP)           // (atom, species) wave-tasks, 16 shells each
#define AEV_BLKS (AEV_TASKS / 4)            // 3584 blocks of 4 waves

typedef __attribute__((ext_vector_type(8))) short short8;
typedef __attribute__((ext_vector_type(4))) float f32x4;
typedef unsigned short ushort_t;

// ---- guaranteed-native transcendentals (single HW instruction) ----
#if !__has_builtin(__builtin_amdgcn_exp2f)
extern "C" __device__ float __ocml_native_exp2_f32(float);
#endif
#if !__has_builtin(__builtin_amdgcn_cosf)
extern "C" __device__ float __ocml_native_cos_f32(float);
#endif
#if !__has_builtin(__builtin_amdgcn_sqrtf)
extern "C" __device__ float __ocml_native_sqrt_f32(float);
#endif

__device__ __forceinline__ float nexp2(float x) {       // 2^x  (v_exp_f32)
#if __has_builtin(__builtin_amdgcn_exp2f)
    return __builtin_amdgcn_exp2f(x);
#else
    return __ocml_native_exp2_f32(x);
#endif
}
__device__ __forceinline__ float ncos_rev(float x) {    // cos(2*pi*x) (v_cos_f32)
#if __has_builtin(__builtin_amdgcn_cosf)
    return __builtin_amdgcn_cosf(x);
#else
    return __ocml_native_cos_f32(x * 6.2831853071795865f);
#endif
}
__device__ __forceinline__ float nsqrt(float x) {       // sqrt(x) (v_sqrt_f32)
#if __has_builtin(__builtin_amdgcn_sqrtf)
    return __builtin_amdgcn_sqrtf(x);
#else
    return __ocml_native_sqrt_f32(x);
#endif
}

__device__ __constant__ float c_shfr[16] = {
    0.9f, 1.16f, 1.43f, 1.69f, 1.96f, 2.22f, 2.49f, 2.75f,
    3.02f, 3.28f, 3.55f, 3.81f, 4.08f, 4.34f, 4.61f, 4.87f};

#define CS_LOG2E  (-23.083120654223414f)   // -16*log2(e)
#define CB_LOG2E  ( 46.166241308446828f)   // +32*log2(e)
#define EA_COEF   ( 12.003222740196175f)   // CB_LOG2E * 0.26 (even->odd shell step)

__device__ __forceinline__ float celu01(float x) {
    return x > 0.f ? x : 0.1f * (nexp2(x * 14.426950f) - 1.f);
}

__device__ __forceinline__ ushort_t f2bf(float v) {   // RNE fp32->bf16
    unsigned u = __float_as_uint(v);
    u += 0x7fffu + ((u >> 16) & 1u);
    return (ushort_t)(u >> 16);
}

// ---------------------------------------------------------------------------
// Kernel 1 (fused): block 0 = deterministic counting sort, 1024 threads
// (2 atoms/thread, two-stage scan, 2-round gather); blocks 1..97 = weight
// repack fp32->bf16 at 1024 threads/block (overlaps the sort).
// NOTE: repack store offset MUST use the branch-LOCAL fragment index g
// (after the -= PREP_G0 adjustments) — R2's global-index store was the bug.
// ---------------------------------------------------------------------------
#define PREP_G0 28672   // 7*16*4*64
#define PREP_G1 43008   // 7*12*8*64
#define PREP_G2 26880   // 7*10*6*64
#define PREP_GT (PREP_G0 + PREP_G1 + PREP_G2)   // 98560 <= 97*1024

__global__ __launch_bounds__(1024) void sortprep_kernel(
    const int* __restrict__ species, const float* __restrict__ coords,
    int* __restrict__ seg, float4* __restrict__ cxyz,
    unsigned* __restrict__ counter,
    const float* __restrict__ W0, const float* __restrict__ W1,
    const float* __restrict__ W2,
    ushort_t* __restrict__ wr0, ushort_t* __restrict__ wr1,
    ushort_t* __restrict__ wr2)
{
    __shared__ int wsum[16][NSP];   // per-wave per-species counts
    __shared__ int wpre[16][NSP];   // inclusive prefix over waves
    __shared__ int sortedL[N_ATOMS];
    int t = threadIdx.x;

    if (blockIdx.x != 0) {
        int g = (blockIdx.x - 1) * 1024 + t;
        if (g < PREP_GT) {
            const float* W; ushort_t* dst; int NT, KS, KREAL, KIN, NOUT;
            if (g < PREP_G0)                 { W = W0; dst = wr0; NT = 16; KS = 4; KREAL = 112; KIN = 1008; NOUT = 256; }
            else if (g < PREP_G0 + PREP_G1)  { g -= PREP_G0; W = W1; dst = wr1; NT = 12; KS = 8; KREAL = 256; KIN = 256; NOUT = 192; }
            else                             { g -= PREP_G0 + PREP_G1; W = W2; dst = wr2; NT = 10; KS = 6; KREAL = 192; KIN = 192; NOUT = 160; }
            int L = g & 63, rest = g >> 6;
            int ks = rest % KS; rest /= KS;
            int nt = rest % NT; int s = rest / NT;
            int n = nt * 16 + (L & 15);
            int k0 = ks * 32 + ((L >> 4) << 3);
            const float* src = W + (size_t)s * KIN * NOUT + n;
            short8 v8;
#pragma unroll
            for (int j = 0; j < 8; ++j) {
                int k = k0 + j;
                float v = (k < KREAL) ? src[(size_t)k * NOUT] : 0.f;
                v8[j] = (short)f2bf(v);
            }
            *(short8*)(dst + (size_t)g * 8) = v8;   // LOCAL g (fixed)
        }
        return;
    }

    // ---- block 0: counting sort (1024 threads = 16 waves, 2 atoms/thread) ----
    int lane = t & 63, wv = t >> 6;
    if (t == 0) counter[0] = 0u;

    int s0 = species[2 * t], s1 = species[2 * t + 1];
    int c[NSP], incl[NSP];
#pragma unroll
    for (int s = 0; s < NSP; ++s) c[s] = (s0 == s ? 1 : 0) + (s1 == s ? 1 : 0);
#pragma unroll
    for (int s = 0; s < NSP; ++s) {
        int v = c[s];
        for (int d = 1; d < 64; d <<= 1) {
            int o = __shfl_up(v, d);
            if (lane >= d) v += o;
        }
        incl[s] = v;
        if (lane == 63) wsum[wv][s] = v;
    }
    __syncthreads();

    // cross-wave scan: 112 lanes (2 waves), width-16 shfl scan per species
    if (t < 112) {
        int s = t >> 4;
        int w = t & 15;
        int v = wsum[w][s];
        for (int d = 1; d < 16; d <<= 1) {
            int o = __shfl_up(v, d, 16);
            if ((t & 15) >= d) v += o;
        }
        wpre[w][s] = v;                     // inclusive over waves 0..w
    }
    __syncthreads();

    int bs[NSP];
    int run = 0;
#pragma unroll
    for (int s = 0; s < NSP; ++s) {
        int tot = wpre[15][s];
        int woff = wpre[wv][s] - wsum[wv][s];          // exclusive wave prefix
        bs[s] = run + woff + incl[s] - c[s];           // exclusive lane prefix
        if (t == 0) seg[s] = run;
        run += tot;
    }
    if (t == 0) seg[NSP] = run;

    // stable scatter of this thread's 2 atoms
    {
        int p0 = bs[s0]++; sortedL[p0] = 2 * t;
        int p1 = bs[s1]++; sortedL[p1] = 2 * t + 1;
    }
    __syncthreads();

    for (int p = t; p < N_ATOMS; p += 1024) {
        int j = sortedL[p];
        cxyz[p] = make_float4(coords[3 * j + 0], coords[3 * j + 1],
                              coords[3 * j + 2], 0.f);
    }
}

// ---------------------------------------------------------------------------
// Kernel 2: radial AEV, one wave-task = (atom, species), all 16 shells.
// Even shells direct (8 exps), odd shells via the exact alternating-grid
// identity; packed-f16 butterfly reduction.  (unchanged — control)
// ---------------------------------------------------------------------------
__global__ __launch_bounds__(256) void aev_kernel(
    const int* __restrict__ seg, const float4* __restrict__ cxyz,
    ushort_t* __restrict__ aevb)
{
    int t = threadIdx.x;
    int jl = t & 63;
    int gid = blockIdx.x * 4 + (t >> 6);   // 0 .. 14335
    int atom = gid / 7;                    // magic-mul const div
    int s = gid - atom * 7;

    float4 ci = cxyz[atom];
    float xi = ci.x, yi = ci.y, zi = ci.z;
    int pb = seg[s], pe = seg[s + 1];

    float BE[8], GE[8], CK[8];
#pragma unroll
    for (int j = 0; j < 8; ++j) {
        float me = c_shfr[2 * j], mo = c_shfr[2 * j + 1];
        BE[j] = CB_LOG2E * me;
        GE[j] = CS_LOG2E * (me * me);
        CK[j] = nexp2(CS_LOG2E * (mo * mo - me * me));   // 2^{CS*(mu_o^2-mu_e^2)}
    }

    float acc[16];
#pragma unroll
    for (int k = 0; k < 16; ++k) acc[k] = 0.f;

    for (int p = pb + jl; p < pe; p += 64) {
        float4 cj = cxyz[p];                       // L1-resident (32KB total)
        float dx = cj.x - xi, dy = cj.y - yi, dz = cj.z - zi;
        float sq = fmaf(dx, dx, fmaf(dy, dy, dz * dz));
        float d  = nsqrt(sq);
        float dc = fminf(d, 5.2f);                 // clamp: exact for fc!=0 pairs
        float fcv = fmaf(0.5f, ncos_rev(dc * 0.09615384615f), 0.5f);  // 0 at dc=5.2
        float fc = (sq > 0.f) ? fcv : 0.f;         // mask self only
        float uc = CS_LOG2E * (dc * dc);
        float ea = nexp2(dc * EA_COEF);            // shared even->odd ratio
        float fe = ea * fc;
#pragma unroll
        for (int j = 0; j < 8; ++j) {
            float ve = nexp2(fmaf(dc, BE[j], uc) + GE[j]);   // even shell, exact
            acc[2 * j]     = fmaf(ve, fc, acc[2 * j]);
            acc[2 * j + 1] = fmaf(ve * fe, CK[j], acc[2 * j + 1]);  // odd shell
        }
    }

    // ---- packed-f16 butterfly reduction (halves shfl+add count) ----
    __half2 h[8];
#pragma unroll
    for (int j = 0; j < 8; ++j)
        h[j] = __floats2half2_rn(acc[2 * j], acc[2 * j + 1]);
#pragma unroll
    for (int off = 32; off > 0; off >>= 1) {
#pragma unroll
        for (int j = 0; j < 8; ++j) {
            unsigned u;
            __builtin_memcpy(&u, &h[j], 4);
            unsigned o = __shfl_down(u, off);
            __half2 oh;
            __builtin_memcpy(&oh, &o, 4);
            h[j] = __hadd2(h[j], oh);              // v_pk_add_f16
        }
    }
    if (jl == 0) {
        short8 lo, hi;
#pragma unroll
        for (int j = 0; j < 8; ++j) {
            float2 f = __half22float2(h[j]);
            int k = 2 * j;
            if (k < 8) {
                lo[k] = (short)f2bf(f.x);
                lo[k + 1] = (short)f2bf(f.y);
            } else {
                hi[k - 8] = (short)f2bf(f.x);
                hi[k - 7] = (short)f2bf(f.y);
            }
        }
        ushort_t* dstp = aevb + (size_t)atom * AEVD + s * 16;
        *(short8*)(dstp) = lo;
        *(short8*)(dstp + 8) = hi;
    }
}

// ---------------------------------------------------------------------------
// Kernel 3: MFMA MLP — 512 threads, 8 waves split the N-tiles.  Next-layer
// weight fragments prefetched BEFORE the current layer's MFMAs (L2 latency
// hides under compute); L0 weights issued before the staging sync.
// Peak live wf state = wf1+wf2 = 28 short8 = 112 VGPR — no spill at 256 cap.
// ---------------------------------------------------------------------------

template<int KSTEPS, int NT>
__device__ __forceinline__ void load_wf(const ushort_t* __restrict__ wrep,
                                        short8 (&wf)[(NT + 7) / 8][KSTEPS],
                                        int lane, int wv)
{
    constexpr int MAXNT = (NT + 7) / 8;
    const int myNT = (NT - wv + 7) / 8;
#pragma unroll
    for (int i = 0; i < MAXNT; ++i) {
        if (i < myNT) {
            int nt = wv + i * 8;
            const ushort_t* wb = wrep + ((size_t)nt * KSTEPS) * 512 + lane * 8;
#pragma unroll
            for (int ks = 0; ks < KSTEPS; ++ks)
                wf[i][ks] = *(const short8*)(wb + ks * 512);
        }
    }
}

template<int KSTEPS, int NT, int SIN, int NOUT, bool OUTF32, int NKSTEPS, int NNT, bool PREF>
__device__ __forceinline__ void compute_layer8(
    const float* __restrict__ bias,
    const ushort_t* Ain,                 // LDS bf16 [16][SIN], swizzled
    ushort_t* Aout,                      // LDS bf16 [16][NOUT], swizzled
    float* Fout,                         // LDS fp32 [16][NOUT] (if OUTF32)
    short8 (&wf)[(NT + 7) / 8][KSTEPS],  // preloaded B fragments for THIS layer
    const ushort_t* __restrict__ nwrep,  // next-layer weight base
    short8 (&nwf)[(NNT + 7) / 8][NKSTEPS],
    int lane, int wv)
{
    constexpr int MAXNT = (NT + 7) / 8;
    const int myNT = (NT - wv + 7) / 8;

    // prefetch NEXT layer's B fragments first (global; latency hides under MFMA)
    if constexpr (PREF) {
        load_wf<NKSTEPS, NNT>(nwrep, nwf, lane, wv);
    }

    // A fragments (shared across this wave's N-tiles)
    short8 af[KSTEPS];
    {
        int m = lane & 15;
        int kb = (lane >> 4) << 3;
        unsigned base = (unsigned)(m * (SIN * 2));
        unsigned swz = (unsigned)((m & 7) << 4);
#pragma unroll
        for (int ks = 0; ks < KSTEPS; ++ks) {
            unsigned addr = (base + (unsigned)((ks * 32 + kb) * 2)) ^ swz;
            af[ks] = *(const short8*)((const char*)Ain + addr);
        }
    }
    f32x4 acc[MAXNT];
#pragma unroll
    for (int i = 0; i < MAXNT; ++i) {
        acc[i] = (f32x4){0.f, 0.f, 0.f, 0.f};
        if (i < myNT) {
#pragma unroll
            for (int ks = 0; ks < KSTEPS; ++ks)
                acc[i] = __builtin_amdgcn_mfma_f32_16x16x32_bf16(af[ks], wf[i][ks], acc[i], 0, 0, 0);
        }
    }
    // epilogue: bias + celu; D layout: n = lane&15, m = (lane>>4)*4 + r
#pragma unroll
    for (int i = 0; i < MAXNT; ++i) {
        if (i < myNT) {
            int nt = wv + i * 8;
            int n = nt * 16 + (lane & 15);
            float bb = bias[n];
#pragma unroll
            for (int r = 0; r < 4; ++r) {
                int m = ((lane >> 4) << 2) + r;
                float v = celu01(acc[i][r] + bb);
                if (OUTF32) {
                    Fout[m * NOUT + n] = v;
                } else {
                    unsigned addr = (unsigned)(m * (NOUT * 2) + n * 2) ^ ((unsigned)((m & 7) << 4));
                    *(ushort_t*)((char*)Aout + addr) = f2bf(v);
                }
            }
        }
    }
    __syncthreads();
}

__global__ __launch_bounds__(512, 1) void mlp_kernel(
    const int* __restrict__ seg, const ushort_t* __restrict__ aevb,
    const ushort_t* __restrict__ wr0, const ushort_t* __restrict__ wr1,
    const ushort_t* __restrict__ wr2,
    const float* __restrict__ b0, const float* __restrict__ b1,
    const float* __restrict__ b2,
    const float* __restrict__ W3, const float* __restrict__ b3,
    float* __restrict__ ebuf, unsigned* __restrict__ counter,
    float* __restrict__ out)
{
    __shared__ __align__(16) ushort_t bufA[16 * 256];
    __shared__ __align__(16) ushort_t bufB[16 * 256];
    __shared__ __align__(16) float h2f[16 * 160];
    __shared__ float ered[MTILE];

    int t = threadIdx.x;
    int lane = t & 63, wv = t >> 6;
    int bid = blockIdx.x;

    int sfound = -1, tile = 0, segbase = 0, na = 0;
    int t0 = 0;
    for (int s = 0; s < NSP; ++s) {
        int beg = seg[s], end = seg[s + 1];
        int n = end - beg;
        int nt = (n + MTILE - 1) >> 4;
        if (sfound < 0 && bid < t0 + nt) {
            sfound = s; tile = bid - t0; segbase = beg;
            int rem = n - tile * MTILE;
            na = rem < MTILE ? rem : MTILE;
        }
        t0 += nt;
    }

    float ssum = 0.f;
    if (sfound >= 0) {
        int s = sfound;
        int row0 = segbase + tile * MTILE;

        float w3v[5];
        {
            const float* w3 = W3 + (size_t)s * 160 + (t & 31);
#pragma unroll
            for (int j = 0; j < 5; ++j) w3v[j] = w3[j * 32];
        }

        // L0 weight fragments issued BEFORE the staging barrier
        short8 wf0[2][4];
        short8 wf1[2][8];
        short8 wf2[2][6];
        short8 wfd[1][1];   // dummy for the last layer
        load_wf<4, 16>(wr0 + (size_t)s * 16 * 4 * 512, wf0, lane, wv);

        // stage AEV rows (bf16, swizzled); rows>=na, cols>=112 zeroed
        if (t < 256) {
            int m = t >> 4, piece = t & 15;
            short8 v = (short8){0,0,0,0,0,0,0,0};
            if (m < na && piece < 14)
                v = *(const short8*)(aevb + (size_t)(row0 + m) * AEVD + piece * 8);
            unsigned addr = (unsigned)(m * 256 + piece * 16) ^ ((unsigned)((m & 7) << 4));
            *(short8*)((char*)bufA + addr) = v;
        }
        __syncthreads();

        compute_layer8<4, 16, 128, 256, false, 8, 12, true>(
            b0 + s * 256, bufA, bufB, nullptr, wf0,
            wr1 + (size_t)s * 12 * 8 * 512, wf1, lane, wv);
        compute_layer8<8, 12, 256, 192, false, 6, 10, true>(
            b1 + s * 192, bufB, bufA, nullptr, wf1,
            wr2 + (size_t)s * 10 * 6 * 512, wf2, lane, wv);
        compute_layer8<6, 10, 192, 160, true, 1, 1, false>(
            b2 + s * 160, bufA, nullptr, h2f, wf2,
            nullptr, wfd, lane, wv);

        // ---- Layer 3: 160 -> 1 per atom (32 lanes per atom, 16 atoms) ----
        {
            int a = t >> 5, l = t & 31;
            float part = 0.f;
#pragma unroll
            for (int j = 0; j < 5; ++j) part = fmaf(h2f[a * 160 + l + j * 32], w3v[j], part);
            for (int off = 16; off; off >>= 1) part += __shfl_down(part, off, 32);
            if (l == 0) ered[a] = part;
        }
        __syncthreads();
        if (t == 0) {
            for (int a = 0; a < na; ++a) ssum += ered[a] + b3[s];
        }
    }

    // completion protocol: last block reduces ebuf in FIXED order (deterministic)
    if (t == 0) {
        ebuf[bid] = ssum;
        __threadfence();
        unsigned old = atomicAdd(counter, 1u);
        if (old == (unsigned)gridDim.x - 1u) {
            __threadfence();
            float tot = 0.f;
            for (int i = 0; i < (int)gridDim.x; ++i) tot += ebuf[i];
            out[0] = tot;
        }
    }
}

extern "C" void kernel_launch(void* const* d_in, const int* in_sizes, int n_in,
                              void* d_out, int out_size, void* d_ws, size_t ws_size,
                              hipStream_t stream)
{
    const int*   species = (const int*)d_in[0];
    const float* coords  = (const float*)d_in[1];
    const float* W0 = (const float*)d_in[2];
    const float* b0 = (const float*)d_in[3];
    const float* W1 = (const float*)d_in[4];
    const float* b1 = (const float*)d_in[5];
    const float* W2 = (const float*)d_in[6];
    const float* b2 = (const float*)d_in[7];
    const float* W3 = (const float*)d_in[8];
    const float* b3 = (const float*)d_in[9];
    float* out = (float*)d_out;

    // Workspace layout: total 2,069,632 B (< 2 MiB)
    char* ws = (char*)d_ws;
    int*      seg     = (int*)(ws);                   // [0, 32)
    unsigned* counter = (unsigned*)(ws + 48);         // [48, 52)
    float*    ebuf    = (float*)(ws + 64);            // 135 f32
    float4*   cxyz    = (float4*)(ws + 1152);         // 2048 float4 (32 KB)
    ushort_t* aevb    = (ushort_t*)(ws + 33920);      // 2048*112 bf16 (448 KB)
    ushort_t* wr0     = (ushort_t*)(ws + 492672);     // 229376 bf16
    ushort_t* wr1     = (ushort_t*)(ws + 951424);     // 344064 bf16
    ushort_t* wr2     = (ushort_t*)(ws + 1639552);    // 215040 bf16

    hipLaunchKernelGGL(sortprep_kernel, dim3(98), dim3(1024), 0, stream,
                       species, coords, seg, cxyz, counter,
                       W0, W1, W2, wr0, wr1, wr2);
    hipLaunchKernelGGL(aev_kernel, dim3(AEV_BLKS), dim3(256), 0, stream,
                       seg, cxyz, aevb);
    hipLaunchKernelGGL(mlp_kernel, dim3(NBLK_MLP), dim3(512), 0, stream,
                       seg, aevb, wr0, wr1, wr2, b0, b1, b2, W3, b3,
                       ebuf, counter, out);
}

// Round 4
// 44.081 us; speedup vs baseline: 1.1060x; 1.0111x over previous
//
#include <hip/hip_runtime.h>
#include <hip/hip_fp16.h>
#include <math.h>

#define N_ATOMS 2048
#define NSP 7
#define AEVD 112      // real radial features; padded to 128 (K-tile) only in LDS
#define MTILE 16      // atoms per MLP block (full 16-row M-tile)
#define NBLK_MLP 135  // max tiles: 2048/16 + 7 slack
#define AEV_TASKS (N_ATOMS * NSP)           // (atom, species) wave-tasks, 16 shells each
#define AEV_BLKS (AEV_TASKS / 4)            // 3584 blocks of 4 waves

typedef __attribute__((ext_vector_type(8))) short short8;
typedef __attribute__((ext_vector_type(4))) float f32x4;
typedef unsigned short ushort_t;

// ---- guaranteed-native transcendentals (single HW instruction) ----
#if !__has_builtin(__builtin_amdgcn_exp2f)
extern "C" __device__ float __ocml_native_exp2_f32(float);
#endif
#if !__has_builtin(__builtin_amdgcn_cosf)
extern "C" __device__ float __ocml_native_cos_f32(float);
#endif
#if !__has_builtin(__builtin_amdgcn_sqrtf)
extern "C" __device__ float __ocml_native_sqrt_f32(float);
#endif

__device__ __forceinline__ float nexp2(float x) {       // 2^x  (v_exp_f32)
#if __has_builtin(__builtin_amdgcn_exp2f)
    return __builtin_amdgcn_exp2f(x);
#else
    return __ocml_native_exp2_f32(x);
#endif
}
__device__ __forceinline__ float ncos_rev(float x) {    // cos(2*pi*x) (v_cos_f32)
#if __has_builtin(__builtin_amdgcn_cosf)
    return __builtin_amdgcn_cosf(x);
#else
    return __ocml_native_cos_f32(x * 6.2831853071795865f);
#endif
}
__device__ __forceinline__ float nsqrt(float x) {       // sqrt(x) (v_sqrt_f32)
#if __has_builtin(__builtin_amdgcn_sqrtf)
    return __builtin_amdgcn_sqrtf(x);
#else
    return __ocml_native_sqrt_f32(x);
#endif
}

__device__ __constant__ float c_shfr[16] = {
    0.9f, 1.16f, 1.43f, 1.69f, 1.96f, 2.22f, 2.49f, 2.75f,
    3.02f, 3.28f, 3.55f, 3.81f, 4.08f, 4.34f, 4.61f, 4.87f};

#define CS_LOG2E  (-23.083120654223414f)   // -16*log2(e)
#define CB_LOG2E  ( 46.166241308446828f)   // +32*log2(e)
#define EA_COEF   ( 12.003222740196175f)   // CB_LOG2E * 0.26 (even->odd shell step)

__device__ __forceinline__ float celu01(float x) {
    return x > 0.f ? x : 0.1f * (nexp2(x * 14.426950f) - 1.f);
}

__device__ __forceinline__ ushort_t f2bf(float v) {   // RNE fp32->bf16
    unsigned u = __float_as_uint(v);
    u += 0x7fffu + ((u >> 16) & 1u);
    return (ushort_t)(u >> 16);
}

// ---------------------------------------------------------------------------
// Kernel 1 (fused): block 0 = deterministic counting sort, 1024 threads
// (2 atoms/thread, two-stage scan, 2-round gather); blocks 1..97 = weight
// repack fp32->bf16 at 1024 threads/block (overlaps the sort).
// NOTE: repack store offset MUST use the branch-LOCAL fragment index g
// (after the -= PREP_G0 adjustments).
// ---------------------------------------------------------------------------
#define PREP_G0 28672   // 7*16*4*64
#define PREP_G1 43008   // 7*12*8*64
#define PREP_G2 26880   // 7*10*6*64
#define PREP_GT (PREP_G0 + PREP_G1 + PREP_G2)   // 98560 <= 97*1024

__global__ __launch_bounds__(1024) void sortprep_kernel(
    const int* __restrict__ species, const float* __restrict__ coords,
    int* __restrict__ seg, float4* __restrict__ cxyz,
    unsigned* __restrict__ counter,
    const float* __restrict__ W0, const float* __restrict__ W1,
    const float* __restrict__ W2,
    ushort_t* __restrict__ wr0, ushort_t* __restrict__ wr1,
    ushort_t* __restrict__ wr2)
{
    __shared__ int wsum[16][NSP];   // per-wave per-species counts
    __shared__ int wpre[16][NSP];   // inclusive prefix over waves
    __shared__ int sortedL[N_ATOMS];
    int t = threadIdx.x;

    if (blockIdx.x != 0) {
        int g = (blockIdx.x - 1) * 1024 + t;
        if (g < PREP_GT) {
            const float* W; ushort_t* dst; int NT, KS, KREAL, KIN, NOUT;
            if (g < PREP_G0)                 { W = W0; dst = wr0; NT = 16; KS = 4; KREAL = 112; KIN = 1008; NOUT = 256; }
            else if (g < PREP_G0 + PREP_G1)  { g -= PREP_G0; W = W1; dst = wr1; NT = 12; KS = 8; KREAL = 256; KIN = 256; NOUT = 192; }
            else                             { g -= PREP_G0 + PREP_G1; W = W2; dst = wr2; NT = 10; KS = 6; KREAL = 192; KIN = 192; NOUT = 160; }
            int L = g & 63, rest = g >> 6;
            int ks = rest % KS; rest /= KS;
            int nt = rest % NT; int s = rest / NT;
            int n = nt * 16 + (L & 15);
            int k0 = ks * 32 + ((L >> 4) << 3);
            const float* src = W + (size_t)s * KIN * NOUT + n;
            short8 v8;
#pragma unroll
            for (int j = 0; j < 8; ++j) {
                int k = k0 + j;
                float v = (k < KREAL) ? src[(size_t)k * NOUT] : 0.f;
                v8[j] = (short)f2bf(v);
            }
            *(short8*)(dst + (size_t)g * 8) = v8;   // LOCAL g
        }
        return;
    }

    // ---- block 0: counting sort (1024 threads = 16 waves, 2 atoms/thread) ----
    int lane = t & 63, wv = t >> 6;
    if (t == 0) counter[0] = 0u;

    int s0 = species[2 * t], s1 = species[2 * t + 1];
    int c[NSP], incl[NSP];
#pragma unroll
    for (int s = 0; s < NSP; ++s) c[s] = (s0 == s ? 1 : 0) + (s1 == s ? 1 : 0);
#pragma unroll
    for (int s = 0; s < NSP; ++s) {
        int v = c[s];
        for (int d = 1; d < 64; d <<= 1) {
            int o = __shfl_up(v, d);
            if (lane >= d) v += o;
        }
        incl[s] = v;
        if (lane == 63) wsum[wv][s] = v;
    }
    __syncthreads();

    // cross-wave scan: 112 lanes (2 waves), width-16 shfl scan per species
    if (t < 112) {
        int s = t >> 4;
        int w = t & 15;
        int v = wsum[w][s];
        for (int d = 1; d < 16; d <<= 1) {
            int o = __shfl_up(v, d, 16);
            if ((t & 15) >= d) v += o;
        }
        wpre[w][s] = v;                     // inclusive over waves 0..w
    }
    __syncthreads();

    int bs[NSP];
    int run = 0;
#pragma unroll
    for (int s = 0; s < NSP; ++s) {
        int tot = wpre[15][s];
        int woff = wpre[wv][s] - wsum[wv][s];          // exclusive wave prefix
        bs[s] = run + woff + incl[s] - c[s];           // exclusive lane prefix
        if (t == 0) seg[s] = run;
        run += tot;
    }
    if (t == 0) seg[NSP] = run;

    // stable scatter of this thread's 2 atoms
    {
        int p0 = bs[s0]++; sortedL[p0] = 2 * t;
        int p1 = bs[s1]++; sortedL[p1] = 2 * t + 1;
    }
    __syncthreads();

    for (int p = t; p < N_ATOMS; p += 1024) {
        int j = sortedL[p];
        cxyz[p] = make_float4(coords[3 * j + 0], coords[3 * j + 1],
                              coords[3 * j + 2], 0.f);
    }
}

// ---------------------------------------------------------------------------
// Kernel 2: radial AEV, one wave-task = (atom, species), all 16 shells.
// R4: self-pair mask (cmp+cndmask per pair) removed — the self pair is
// accumulated and then subtracted analytically on the ONE lane that
// processed p==atom (bit-reproducible: at sq=0 the in-loop path yields
// exactly nexp2(GE[j]) and nexp2(GE[j])*CK[j]).  Explicit pointer-bump
// neighbor addressing.  Even shells direct (8 exps), odd shells via the
// exact alternating-grid identity; packed-f16 butterfly reduction.
// ---------------------------------------------------------------------------
__global__ __launch_bounds__(256) void aev_kernel(
    const int* __restrict__ seg, const float4* __restrict__ cxyz,
    ushort_t* __restrict__ aevb)
{
    int t = threadIdx.x;
    int jl = t & 63;
    int gid = blockIdx.x * 4 + (t >> 6);   // 0 .. 14335
    int atom = gid / 7;                    // magic-mul const div
    int s = gid - atom * 7;

    float4 ci = cxyz[atom];
    float xi = ci.x, yi = ci.y, zi = ci.z;
    int pb = seg[s], pe = seg[s + 1];

    float BE[8], GE[8], CK[8];
#pragma unroll
    for (int j = 0; j < 8; ++j) {
        float me = c_shfr[2 * j], mo = c_shfr[2 * j + 1];
        BE[j] = CB_LOG2E * me;
        GE[j] = CS_LOG2E * (me * me);
        CK[j] = nexp2(CS_LOG2E * (mo * mo - me * me));   // 2^{CS*(mu_o^2-mu_e^2)}
    }

    float acc[16];
#pragma unroll
    for (int k = 0; k < 16; ++k) acc[k] = 0.f;

    const float4* pj = cxyz + pb + jl;
    for (int n = pe - pb - jl; n > 0; n -= 64, pj += 64) {
        float4 cj = *pj;                           // L1-resident (32KB total)
        float dx = cj.x - xi, dy = cj.y - yi, dz = cj.z - zi;
        float sq = fmaf(dx, dx, fmaf(dy, dy, dz * dz));
        float d  = nsqrt(sq);
        float dc = fminf(d, 5.2f);                 // clamp: keeps ea finite; fc(5.2)=0
        float fc = fmaf(0.5f, ncos_rev(dc * 0.09615384615f), 0.5f);  // no self mask
        float uc = CS_LOG2E * sq;
        float ea = nexp2(dc * EA_COEF);            // shared even->odd ratio
        float fe = ea * fc;
#pragma unroll
        for (int j = 0; j < 8; ++j) {
            float ve = nexp2(fmaf(dc, BE[j], uc) + GE[j]);   // even shell, exact
            acc[2 * j]     = fmaf(ve, fc, acc[2 * j]);
            acc[2 * j + 1] = fmaf(ve * fe, CK[j], acc[2 * j + 1]);  // odd shell
        }
    }

    // subtract the self-pair (exact replica of in-loop values at sq=0),
    // only on the lane that actually processed p == atom
    if (pb <= atom && atom < pe && ((atom - pb) & 63) == jl) {
#pragma unroll
        for (int j = 0; j < 8; ++j) {
            float sv = nexp2(GE[j]);
            acc[2 * j]     -= sv;
            acc[2 * j + 1] -= sv * CK[j];
        }
    }

    // ---- packed-f16 butterfly reduction (halves shfl+add count) ----
    __half2 h[8];
#pragma unroll
    for (int j = 0; j < 8; ++j)
        h[j] = __floats2half2_rn(acc[2 * j], acc[2 * j + 1]);
#pragma unroll
    for (int off = 32; off > 0; off >>= 1) {
#pragma unroll
        for (int j = 0; j < 8; ++j) {
            unsigned u;
            __builtin_memcpy(&u, &h[j], 4);
            unsigned o = __shfl_down(u, off);
            __half2 oh;
            __builtin_memcpy(&oh, &o, 4);
            h[j] = __hadd2(h[j], oh);              // v_pk_add_f16
        }
    }
    if (jl == 0) {
        short8 lo, hi;
#pragma unroll
        for (int j = 0; j < 8; ++j) {
            float2 f = __half22float2(h[j]);
            int k = 2 * j;
            if (k < 8) {
                lo[k] = (short)f2bf(f.x);
                lo[k + 1] = (short)f2bf(f.y);
            } else {
                hi[k - 8] = (short)f2bf(f.x);
                hi[k - 7] = (short)f2bf(f.y);
            }
        }
        ushort_t* dstp = aevb + (size_t)atom * AEVD + s * 16;
        *(short8*)(dstp) = lo;
        *(short8*)(dstp + 8) = hi;
    }
}

// ---------------------------------------------------------------------------
// Kernel 3: MFMA MLP — 512 threads, 8 waves split the N-tiles.  Next-layer
// weight fragments prefetched BEFORE the current layer's MFMAs (L2 latency
// hides under compute); L0 weights issued before the staging sync.
// Peak live wf state = wf1+wf2 = 28 short8 = 112 VGPR — no spill at 256 cap.
// ---------------------------------------------------------------------------

template<int KSTEPS, int NT>
__device__ __forceinline__ void load_wf(const ushort_t* __restrict__ wrep,
                                        short8 (&wf)[(NT + 7) / 8][KSTEPS],
                                        int lane, int wv)
{
    constexpr int MAXNT = (NT + 7) / 8;
    const int myNT = (NT - wv + 7) / 8;
#pragma unroll
    for (int i = 0; i < MAXNT; ++i) {
        if (i < myNT) {
            int nt = wv + i * 8;
            const ushort_t* wb = wrep + ((size_t)nt * KSTEPS) * 512 + lane * 8;
#pragma unroll
            for (int ks = 0; ks < KSTEPS; ++ks)
                wf[i][ks] = *(const short8*)(wb + ks * 512);
        }
    }
}

template<int KSTEPS, int NT, int SIN, int NOUT, bool OUTF32, int NKSTEPS, int NNT, bool PREF>
__device__ __forceinline__ void compute_layer8(
    const float* __restrict__ bias,
    const ushort_t* Ain,                 // LDS bf16 [16][SIN], swizzled
    ushort_t* Aout,                      // LDS bf16 [16][NOUT], swizzled
    float* Fout,                         // LDS fp32 [16][NOUT] (if OUTF32)
    short8 (&wf)[(NT + 7) / 8][KSTEPS],  // preloaded B fragments for THIS layer
    const ushort_t* __restrict__ nwrep,  // next-layer weight base
    short8 (&nwf)[(NNT + 7) / 8][NKSTEPS],
    int lane, int wv)
{
    constexpr int MAXNT = (NT + 7) / 8;
    const int myNT = (NT - wv + 7) / 8;

    // prefetch NEXT layer's B fragments first (global; latency hides under MFMA)
    if constexpr (PREF) {
        load_wf<NKSTEPS, NNT>(nwrep, nwf, lane, wv);
    }

    // A fragments (shared across this wave's N-tiles)
    short8 af[KSTEPS];
    {
        int m = lane & 15;
        int kb = (lane >> 4) << 3;
        unsigned base = (unsigned)(m * (SIN * 2));
        unsigned swz = (unsigned)((m & 7) << 4);
#pragma unroll
        for (int ks = 0; ks < KSTEPS; ++ks) {
            unsigned addr = (base + (unsigned)((ks * 32 + kb) * 2)) ^ swz;
            af[ks] = *(const short8*)((const char*)Ain + addr);
        }
    }
    f32x4 acc[MAXNT];
#pragma unroll
    for (int i = 0; i < MAXNT; ++i) {
        acc[i] = (f32x4){0.f, 0.f, 0.f, 0.f};
        if (i < myNT) {
#pragma unroll
            for (int ks = 0; ks < KSTEPS; ++ks)
                acc[i] = __builtin_amdgcn_mfma_f32_16x16x32_bf16(af[ks], wf[i][ks], acc[i], 0, 0, 0);
        }
    }
    // epilogue: bias + celu; D layout: n = lane&15, m = (lane>>4)*4 + r
#pragma unroll
    for (int i = 0; i < MAXNT; ++i) {
        if (i < myNT) {
            int nt = wv + i * 8;
            int n = nt * 16 + (lane & 15);
            float bb = bias[n];
#pragma unroll
            for (int r = 0; r < 4; ++r) {
                int m = ((lane >> 4) << 2) + r;
                float v = celu01(acc[i][r] + bb);
                if (OUTF32) {
                    Fout[m * NOUT + n] = v;
                } else {
                    unsigned addr = (unsigned)(m * (NOUT * 2) + n * 2) ^ ((unsigned)((m & 7) << 4));
                    *(ushort_t*)((char*)Aout + addr) = f2bf(v);
                }
            }
        }
    }
    __syncthreads();
}

__global__ __launch_bounds__(512, 1) void mlp_kernel(
    const int* __restrict__ seg, const ushort_t* __restrict__ aevb,
    const ushort_t* __restrict__ wr0, const ushort_t* __restrict__ wr1,
    const ushort_t* __restrict__ wr2,
    const float* __restrict__ b0, const float* __restrict__ b1,
    const float* __restrict__ b2,
    const float* __restrict__ W3, const float* __restrict__ b3,
    float* __restrict__ ebuf, unsigned* __restrict__ counter,
    float* __restrict__ out)
{
    __shared__ __align__(16) ushort_t bufA[16 * 256];
    __shared__ __align__(16) ushort_t bufB[16 * 256];
    __shared__ __align__(16) float h2f[16 * 160];
    __shared__ float ered[MTILE];

    int t = threadIdx.x;
    int lane = t & 63, wv = t >> 6;
    int bid = blockIdx.x;

    int sfound = -1, tile = 0, segbase = 0, na = 0;
    int t0 = 0;
    for (int s = 0; s < NSP; ++s) {
        int beg = seg[s], end = seg[s + 1];
        int n = end - beg;
        int nt = (n + MTILE - 1) >> 4;
        if (sfound < 0 && bid < t0 + nt) {
            sfound = s; tile = bid - t0; segbase = beg;
            int rem = n - tile * MTILE;
            na = rem < MTILE ? rem : MTILE;
        }
        t0 += nt;
    }

    float ssum = 0.f;
    if (sfound >= 0) {
        int s = sfound;
        int row0 = segbase + tile * MTILE;

        float w3v[5];
        {
            const float* w3 = W3 + (size_t)s * 160 + (t & 31);
#pragma unroll
            for (int j = 0; j < 5; ++j) w3v[j] = w3[j * 32];
        }

        // L0 weight fragments issued BEFORE the staging barrier
        short8 wf0[2][4];
        short8 wf1[2][8];
        short8 wf2[2][6];
        short8 wfd[1][1];   // dummy for the last layer
        load_wf<4, 16>(wr0 + (size_t)s * 16 * 4 * 512, wf0, lane, wv);

        // stage AEV rows (bf16, swizzled); rows>=na, cols>=112 zeroed
        if (t < 256) {
            int m = t >> 4, piece = t & 15;
            short8 v = (short8){0,0,0,0,0,0,0,0};
            if (m < na && piece < 14)
                v = *(const short8*)(aevb + (size_t)(row0 + m) * AEVD + piece * 8);
            unsigned addr = (unsigned)(m * 256 + piece * 16) ^ ((unsigned)((m & 7) << 4));
            *(short8*)((char*)bufA + addr) = v;
        }
        __syncthreads();

        compute_layer8<4, 16, 128, 256, false, 8, 12, true>(
            b0 + s * 256, bufA, bufB, nullptr, wf0,
            wr1 + (size_t)s * 12 * 8 * 512, wf1, lane, wv);
        compute_layer8<8, 12, 256, 192, false, 6, 10, true>(
            b1 + s * 192, bufB, bufA, nullptr, wf1,
            wr2 + (size_t)s * 10 * 6 * 512, wf2, lane, wv);
        compute_layer8<6, 10, 192, 160, true, 1, 1, false>(
            b2 + s * 160, bufA, nullptr, h2f, wf2,
            nullptr, wfd, lane, wv);

        // ---- Layer 3: 160 -> 1 per atom (32 lanes per atom, 16 atoms) ----
        {
            int a = t >> 5, l = t & 31;
            float part = 0.f;
#pragma unroll
            for (int j = 0; j < 5; ++j) part = fmaf(h2f[a * 160 + l + j * 32], w3v[j], part);
            for (int off = 16; off; off >>= 1) part += __shfl_down(part, off, 32);
            if (l == 0) ered[a] = part;
        }
        __syncthreads();
        if (t == 0) {
            for (int a = 0; a < na; ++a) ssum += ered[a] + b3[s];
        }
    }

    // completion protocol: last block reduces ebuf in FIXED order (deterministic)
    if (t == 0) {
        ebuf[bid] = ssum;
        __threadfence();
        unsigned old = atomicAdd(counter, 1u);
        if (old == (unsigned)gridDim.x - 1u) {
            __threadfence();
            float tot = 0.f;
            for (int i = 0; i < (int)gridDim.x; ++i) tot += ebuf[i];
            out[0] = tot;
        }
    }
}

extern "C" void kernel_launch(void* const* d_in, const int* in_sizes, int n_in,
                              void* d_out, int out_size, void* d_ws, size_t ws_size,
                              hipStream_t stream)
{
    const int*   species = (const int*)d_in[0];
    const float* coords  = (const float*)d_in[1];
    const float* W0 = (const float*)d_in[2];
    const float* b0 = (const float*)d_in[3];
    const float* W1 = (const float*)d_in[4];
    const float* b1 = (const float*)d_in[5];
    const float* W2 = (const float*)d_in[6];
    const float* b2 = (const float*)d_in[7];
    const float* W3 = (const float*)d_in[8];
    const float* b3 = (const float*)d_in[9];
    float* out = (float*)d_out;

    // Workspace layout: total 2,069,632 B (< 2 MiB)
    char* ws = (char*)d_ws;
    int*      seg     = (int*)(ws);                   // [0, 32)
    unsigned* counter = (unsigned*)(ws + 48);         // [48, 52)
    float*    ebuf    = (float*)(ws + 64);            // 135 f32
    float4*   cxyz    = (float4*)(ws + 1152);         // 2048 float4 (32 KB)
    ushort_t* aevb    = (ushort_t*)(ws + 33920);      // 2048*112 bf16 (448 KB)
    ushort_t* wr0     = (ushort_t*)(ws + 492672);     // 229376 bf16
    ushort_t* wr1     = (ushort_t*)(ws + 951424);     // 344064 bf16
    ushort_t* wr2     = (ushort_t*)(ws + 1639552);    // 215040 bf16

    hipLaunchKernelGGL(sortprep_kernel, dim3(98), dim3(1024), 0, stream,
                       species, coords, seg, cxyz, counter,
                       W0, W1, W2, wr0, wr1, wr2);
    hipLaunchKernelGGL(aev_kernel, dim3(AEV_BLKS), dim3(256), 0, stream,
                       seg, cxyz, aevb);
    hipLaunchKernelGGL(mlp_kernel, dim3(NBLK_MLP), dim3(512), 0, stream,
                       seg, aevb, wr0, wr1, wr2, b0, b1, b2, W3, b3,
                       ebuf, counter, out);
}

// Round 5
// 41.395 us; speedup vs baseline: 1.1777x; 1.0649x over previous
//
#include <hip/hip_runtime.h>
#include <hip/hip_fp16.h>
#include <math.h>

#define N_ATOMS 2048
#define NSP 7
#define AEVD 112      // real radial features; padded to 128 (K-tile) only in LDS
#define MTILE 16      // atoms per MLP block (full 16-row M-tile)
#define NBLK_MLP 135  // max tiles: 2048/16 + 7 slack
#define AEV_TASKS (N_ATOMS * NSP)           // (atom, species) wave-tasks, 16 shells each
#define AEV_BLKS (AEV_TASKS / 4)            // 3584 blocks of 4 waves

typedef __attribute__((ext_vector_type(8))) short short8;
typedef __attribute__((ext_vector_type(4))) float f32x4;
typedef __attribute__((ext_vector_type(2))) float f32x2;
typedef unsigned short ushort_t;

// ---- guaranteed-native transcendentals (single HW instruction) ----
#if !__has_builtin(__builtin_amdgcn_exp2f)
extern "C" __device__ float __ocml_native_exp2_f32(float);
#endif
#if !__has_builtin(__builtin_amdgcn_cosf)
extern "C" __device__ float __ocml_native_cos_f32(float);
#endif
#if !__has_builtin(__builtin_amdgcn_sqrtf)
extern "C" __device__ float __ocml_native_sqrt_f32(float);
#endif

__device__ __forceinline__ float nexp2(float x) {       // 2^x  (v_exp_f32)
#if __has_builtin(__builtin_amdgcn_exp2f)
    return __builtin_amdgcn_exp2f(x);
#else
    return __ocml_native_exp2_f32(x);
#endif
}
__device__ __forceinline__ float ncos_rev(float x) {    // cos(2*pi*x) (v_cos_f32)
#if __has_builtin(__builtin_amdgcn_cosf)
    return __builtin_amdgcn_cosf(x);
#else
    return __ocml_native_cos_f32(x * 6.2831853071795865f);
#endif
}
__device__ __forceinline__ float nsqrt(float x) {       // sqrt(x) (v_sqrt_f32)
#if __has_builtin(__builtin_amdgcn_sqrtf)
    return __builtin_amdgcn_sqrtf(x);
#else
    return __ocml_native_sqrt_f32(x);
#endif
}

#define CS_LOG2E  (-23.083120654223414f)   // -16*log2(e)
#define CB_LOG2E  ( 46.166241308446828f)   // +32*log2(e)
#define EA_COEF   ( 12.003222740196175f)   // CB_LOG2E * 0.26 (even->odd shell step)
#define EB_COEF   ( 24.468107893476819f)   // CB_LOG2E * 0.53 (even->even shell step)

__device__ __forceinline__ float celu01(float x) {
    return x > 0.f ? x : 0.1f * (nexp2(x * 14.426950f) - 1.f);
}

__device__ __forceinline__ ushort_t f2bf(float v) {   // RNE fp32->bf16
    unsigned u = __float_as_uint(v);
    u += 0x7fffu + ((u >> 16) & 1u);
    return (ushort_t)(u >> 16);
}

// ---------------------------------------------------------------------------
// Kernel 1 (fused): block 0 = deterministic counting sort, 1024 threads
// (2 atoms/thread, two-stage scan, 2-round gather); blocks 1..97 = weight
// repack fp32->bf16 at 1024 threads/block (overlaps the sort).
// NOTE: repack store offset MUST use the branch-LOCAL fragment index g
// (after the -= PREP_G0 adjustments).
// ---------------------------------------------------------------------------
#define PREP_G0 28672   // 7*16*4*64
#define PREP_G1 43008   // 7*12*8*64
#define PREP_G2 26880   // 7*10*6*64
#define PREP_GT (PREP_G0 + PREP_G1 + PREP_G2)   // 98560 <= 97*1024

__global__ __launch_bounds__(1024) void sortprep_kernel(
    const int* __restrict__ species, const float* __restrict__ coords,
    int* __restrict__ seg, float4* __restrict__ cxyz,
    unsigned* __restrict__ counter,
    const float* __restrict__ W0, const float* __restrict__ W1,
    const float* __restrict__ W2,
    ushort_t* __restrict__ wr0, ushort_t* __restrict__ wr1,
    ushort_t* __restrict__ wr2)
{
    __shared__ int wsum[16][NSP];   // per-wave per-species counts
    __shared__ int wpre[16][NSP];   // inclusive prefix over waves
    __shared__ int sortedL[N_ATOMS];
    int t = threadIdx.x;

    if (blockIdx.x != 0) {
        int g = (blockIdx.x - 1) * 1024 + t;
        if (g < PREP_GT) {
            const float* W; ushort_t* dst; int NT, KS, KREAL, KIN, NOUT;
            if (g < PREP_G0)                 { W = W0; dst = wr0; NT = 16; KS = 4; KREAL = 112; KIN = 1008; NOUT = 256; }
            else if (g < PREP_G0 + PREP_G1)  { g -= PREP_G0; W = W1; dst = wr1; NT = 12; KS = 8; KREAL = 256; KIN = 256; NOUT = 192; }
            else                             { g -= PREP_G0 + PREP_G1; W = W2; dst = wr2; NT = 10; KS = 6; KREAL = 192; KIN = 192; NOUT = 160; }
            int L = g & 63, rest = g >> 6;
            int ks = rest % KS; rest /= KS;
            int nt = rest % NT; int s = rest / NT;
            int n = nt * 16 + (L & 15);
            int k0 = ks * 32 + ((L >> 4) << 3);
            const float* src = W + (size_t)s * KIN * NOUT + n;
            short8 v8;
#pragma unroll
            for (int j = 0; j < 8; ++j) {
                int k = k0 + j;
                float v = (k < KREAL) ? src[(size_t)k * NOUT] : 0.f;
                v8[j] = (short)f2bf(v);
            }
            *(short8*)(dst + (size_t)g * 8) = v8;   // LOCAL g
        }
        return;
    }

    // ---- block 0: counting sort (1024 threads = 16 waves, 2 atoms/thread) ----
    int lane = t & 63, wv = t >> 6;
    if (t == 0) counter[0] = 0u;

    int s0 = species[2 * t], s1 = species[2 * t + 1];
    int c[NSP], incl[NSP];
#pragma unroll
    for (int s = 0; s < NSP; ++s) c[s] = (s0 == s ? 1 : 0) + (s1 == s ? 1 : 0);
#pragma unroll
    for (int s = 0; s < NSP; ++s) {
        int v = c[s];
        for (int d = 1; d < 64; d <<= 1) {
            int o = __shfl_up(v, d);
            if (lane >= d) v += o;
        }
        incl[s] = v;
        if (lane == 63) wsum[wv][s] = v;
    }
    __syncthreads();

    // cross-wave scan: 112 lanes (2 waves), width-16 shfl scan per species
    if (t < 112) {
        int s = t >> 4;
        int w = t & 15;
        int v = wsum[w][s];
        for (int d = 1; d < 16; d <<= 1) {
            int o = __shfl_up(v, d, 16);
            if ((t & 15) >= d) v += o;
        }
        wpre[w][s] = v;                     // inclusive over waves 0..w
    }
    __syncthreads();

    int bs[NSP];
    int run = 0;
#pragma unroll
    for (int s = 0; s < NSP; ++s) {
        int tot = wpre[15][s];
        int woff = wpre[wv][s] - wsum[wv][s];          // exclusive wave prefix
        bs[s] = run + woff + incl[s] - c[s];           // exclusive lane prefix
        if (t == 0) seg[s] = run;
        run += tot;
    }
    if (t == 0) seg[NSP] = run;

    // stable scatter of this thread's 2 atoms
    {
        int p0 = bs[s0]++; sortedL[p0] = 2 * t;
        int p1 = bs[s1]++; sortedL[p1] = 2 * t + 1;
    }
    __syncthreads();

    for (int p = t; p < N_ATOMS; p += 1024) {
        int j = sortedL[p];
        cxyz[p] = make_float4(coords[3 * j + 0], coords[3 * j + 1],
                              coords[3 * j + 2], 0.f);
    }
}

// ---------------------------------------------------------------------------
// Kernel 2: radial AEV, one wave-task = (atom, species), all 16 shells.
// R5: second-level ladder — even shells are ALSO uniform (step 0.53), so
// 2 anchor exps (mu=0.9, 3.02) + shared eb=2^(24.468*d) give all 8 even
// shells via 3 packed chain muls; odd shells via shared ea (step 0.26)
// with the per-shell constant CK[j] moved OUT of the pair loop
// (O[j] = CK[j]*sum(ve*fe)).  Accumulation in packed f32 (v_pk_fma_f32):
// accE += ve*{fc,fc}, accO += ve*{fe,fe}.  Self-pair subtracted post-loop
// by replicating the ladder at sq=0 (exp2(0)=1 and *1.0 are exact).
// ---------------------------------------------------------------------------
__global__ __launch_bounds__(256) void aev_kernel(
    const int* __restrict__ seg, const float4* __restrict__ cxyz,
    ushort_t* __restrict__ aevb)
{
    int t = threadIdx.x;
    int jl = t & 63;
    int gid = blockIdx.x * 4 + (t >> 6);   // 0 .. 14335
    int atom = gid / 7;                    // magic-mul const div
    int s = gid - atom * 7;

    float4 ci = cxyz[atom];
    float xi = ci.x, yi = ci.y, zi = ci.z;
    int pb = seg[s], pe = seg[s + 1];

    // anchor constants (compile-time folded literal arithmetic)
    const float BE_A0 = CB_LOG2E * 0.9f;
    const float GE_A0 = CS_LOG2E * (0.9f * 0.9f);
    const float BE_A1 = CB_LOG2E * 3.02f;
    const float GE_A1 = CS_LOG2E * (3.02f * 3.02f);

    // even-shell mus (ladder order; SHFR[2j] = mu_e[j])
    const float mu_e[8] = {0.9f, 1.43f, 1.96f, 2.49f, 3.02f, 3.55f, 4.08f, 4.61f};

    // chain constants: cke[i] = {lo-chain step i, hi-chain step i}
    f32x2 cke[3];
#pragma unroll
    for (int i = 0; i < 3; ++i) {
        cke[i][0] = nexp2(CS_LOG2E * (mu_e[i + 1] * mu_e[i + 1] - mu_e[i] * mu_e[i]));
        cke[i][1] = nexp2(CS_LOG2E * (mu_e[i + 5] * mu_e[i + 5] - mu_e[i + 4] * mu_e[i + 4]));
    }
    // odd-shell post-multipliers (loop-invariant, applied after the pair loop)
    float cko[8];
#pragma unroll
    for (int j = 0; j < 8; ++j) {
        float me = mu_e[j], mo = me + 0.26f;
        cko[j] = nexp2(CS_LOG2E * (mo * mo - me * me));
    }

    f32x2 accE[4], accO[4];
#pragma unroll
    for (int i = 0; i < 4; ++i) {
        accE[i] = (f32x2){0.f, 0.f};
        accO[i] = (f32x2){0.f, 0.f};
    }

    const float4* pj = cxyz + pb + jl;
    for (int n = pe - pb - jl; n > 0; n -= 64, pj += 64) {
        float4 cj = *pj;                           // L1-resident (32KB total)
        float dx = cj.x - xi, dy = cj.y - yi, dz = cj.z - zi;
        float sq = fmaf(dx, dx, fmaf(dy, dy, dz * dz));
        float d  = nsqrt(sq);
        float dc = fminf(d, 5.2f);                 // clamp: keeps eb/ea finite; fc(5.2)=0
        float fc = fmaf(0.5f, ncos_rev(dc * 0.09615384615f), 0.5f);
        float uc = CS_LOG2E * sq;
        float ea = nexp2(dc * EA_COEF);            // even->odd ratio (shared)
        float fe = ea * fc;
        float ebv = nexp2(dc * EB_COEF);           // even->even ratio (shared)
        f32x2 eb2 = (f32x2){ebv, ebv};
        f32x2 fc2 = (f32x2){fc, fc};
        f32x2 fe2 = (f32x2){fe, fe};
        f32x2 ek0 = eb2 * cke[0];
        f32x2 ek1 = eb2 * cke[1];
        f32x2 ek2 = eb2 * cke[2];
        f32x2 ve = (f32x2){ nexp2(fmaf(dc, BE_A0, uc) + GE_A0),
                            nexp2(fmaf(dc, BE_A1, uc) + GE_A1) };
        accE[0] = ve * fc2 + accE[0];  accO[0] = ve * fe2 + accO[0];
        ve = ve * ek0;
        accE[1] = ve * fc2 + accE[1];  accO[1] = ve * fe2 + accO[1];
        ve = ve * ek1;
        accE[2] = ve * fc2 + accE[2];  accO[2] = ve * fe2 + accO[2];
        ve = ve * ek2;
        accE[3] = ve * fc2 + accE[3];  accO[3] = ve * fe2 + accO[3];
    }

    // subtract the self-pair: exact replica of the in-loop ladder at sq=0
    // (dc=0 -> fc=1, fe=1, eb=1 -> ek=cke; fma with multiplier 1.0 == add)
    if (pb <= atom && atom < pe && ((atom - pb) & 63) == jl) {
        f32x2 ve = (f32x2){ nexp2(GE_A0), nexp2(GE_A1) };
        accE[0] -= ve;  accO[0] -= ve;
        ve = ve * cke[0];
        accE[1] -= ve;  accO[1] -= ve;
        ve = ve * cke[1];
        accE[2] -= ve;  accO[2] -= ve;
        ve = ve * cke[2];
        accE[3] -= ve;  accO[3] -= ve;
    }

    // unpack: E[j]/O[j] in SHFR order (even idx 2j, odd idx 2j+1)
    float accf[16];
#pragma unroll
    for (int j = 0; j < 8; ++j) {
        float E = (j < 4) ? accE[j][0] : accE[j - 4][1];
        float O = ((j < 4) ? accO[j][0] : accO[j - 4][1]) * cko[j];
        accf[2 * j] = E;
        accf[2 * j + 1] = O;
    }

    // ---- packed-f16 butterfly reduction (halves shfl+add count) ----
    __half2 h[8];
#pragma unroll
    for (int j = 0; j < 8; ++j)
        h[j] = __floats2half2_rn(accf[2 * j], accf[2 * j + 1]);
#pragma unroll
    for (int off = 32; off > 0; off >>= 1) {
#pragma unroll
        for (int j = 0; j < 8; ++j) {
            unsigned u;
            __builtin_memcpy(&u, &h[j], 4);
            unsigned o = __shfl_down(u, off);
            __half2 oh;
            __builtin_memcpy(&oh, &o, 4);
            h[j] = __hadd2(h[j], oh);              // v_pk_add_f16
        }
    }
    if (jl == 0) {
        short8 lo, hi;
#pragma unroll
        for (int j = 0; j < 8; ++j) {
            float2 f = __half22float2(h[j]);
            int k = 2 * j;
            if (k < 8) {
                lo[k] = (short)f2bf(f.x);
                lo[k + 1] = (short)f2bf(f.y);
            } else {
                hi[k - 8] = (short)f2bf(f.x);
                hi[k - 7] = (short)f2bf(f.y);
            }
        }
        ushort_t* dstp = aevb + (size_t)atom * AEVD + s * 16;
        *(short8*)(dstp) = lo;
        *(short8*)(dstp + 8) = hi;
    }
}

// ---------------------------------------------------------------------------
// Kernel 3: MFMA MLP — 512 threads, 8 waves split the N-tiles.  Next-layer
// weight fragments prefetched BEFORE the current layer's MFMAs (L2 latency
// hides under compute); L0 weights issued before the staging sync.
// Peak live wf state = wf1+wf2 = 28 short8 = 112 VGPR — no spill at 256 cap.
// ---------------------------------------------------------------------------

template<int KSTEPS, int NT>
__device__ __forceinline__ void load_wf(const ushort_t* __restrict__ wrep,
                                        short8 (&wf)[(NT + 7) / 8][KSTEPS],
                                        int lane, int wv)
{
    constexpr int MAXNT = (NT + 7) / 8;
    const int myNT = (NT - wv + 7) / 8;
#pragma unroll
    for (int i = 0; i < MAXNT; ++i) {
        if (i < myNT) {
            int nt = wv + i * 8;
            const ushort_t* wb = wrep + ((size_t)nt * KSTEPS) * 512 + lane * 8;
#pragma unroll
            for (int ks = 0; ks < KSTEPS; ++ks)
                wf[i][ks] = *(const short8*)(wb + ks * 512);
        }
    }
}

template<int KSTEPS, int NT, int SIN, int NOUT, bool OUTF32, int NKSTEPS, int NNT, bool PREF>
__device__ __forceinline__ void compute_layer8(
    const float* __restrict__ bias,
    const ushort_t* Ain,                 // LDS bf16 [16][SIN], swizzled
    ushort_t* Aout,                      // LDS bf16 [16][NOUT], swizzled
    float* Fout,                         // LDS fp32 [16][NOUT] (if OUTF32)
    short8 (&wf)[(NT + 7) / 8][KSTEPS],  // preloaded B fragments for THIS layer
    const ushort_t* __restrict__ nwrep,  // next-layer weight base
    short8 (&nwf)[(NNT + 7) / 8][NKSTEPS],
    int lane, int wv)
{
    constexpr int MAXNT = (NT + 7) / 8;
    const int myNT = (NT - wv + 7) / 8;

    // prefetch NEXT layer's B fragments first (global; latency hides under MFMA)
    if constexpr (PREF) {
        load_wf<NKSTEPS, NNT>(nwrep, nwf, lane, wv);
    }

    // A fragments (shared across this wave's N-tiles)
    short8 af[KSTEPS];
    {
        int m = lane & 15;
        int kb = (lane >> 4) << 3;
        unsigned base = (unsigned)(m * (SIN * 2));
        unsigned swz = (unsigned)((m & 7) << 4);
#pragma unroll
        for (int ks = 0; ks < KSTEPS; ++ks) {
            unsigned addr = (base + (unsigned)((ks * 32 + kb) * 2)) ^ swz;
            af[ks] = *(const short8*)((const char*)Ain + addr);
        }
    }
    f32x4 acc[MAXNT];
#pragma unroll
    for (int i = 0; i < MAXNT; ++i) {
        acc[i] = (f32x4){0.f, 0.f, 0.f, 0.f};
        if (i < myNT) {
#pragma unroll
            for (int ks = 0; ks < KSTEPS; ++ks)
                acc[i] = __builtin_amdgcn_mfma_f32_16x16x32_bf16(af[ks], wf[i][ks], acc[i], 0, 0, 0);
        }
    }
    // epilogue: bias + celu; D layout: n = lane&15, m = (lane>>4)*4 + r
#pragma unroll
    for (int i = 0; i < MAXNT; ++i) {
        if (i < myNT) {
            int nt = wv + i * 8;
            int n = nt * 16 + (lane & 15);
            float bb = bias[n];
#pragma unroll
            for (int r = 0; r < 4; ++r) {
                int m = ((lane >> 4) << 2) + r;
                float v = celu01(acc[i][r] + bb);
                if (OUTF32) {
                    Fout[m * NOUT + n] = v;
                } else {
                    unsigned addr = (unsigned)(m * (NOUT * 2) + n * 2) ^ ((unsigned)((m & 7) << 4));
                    *(ushort_t*)((char*)Aout + addr) = f2bf(v);
                }
            }
        }
    }
    __syncthreads();
}

__global__ __launch_bounds__(512, 1) void mlp_kernel(
    const int* __restrict__ seg, const ushort_t* __restrict__ aevb,
    const ushort_t* __restrict__ wr0, const ushort_t* __restrict__ wr1,
    const ushort_t* __restrict__ wr2,
    const float* __restrict__ b0, const float* __restrict__ b1,
    const float* __restrict__ b2,
    const float* __restrict__ W3, const float* __restrict__ b3,
    float* __restrict__ ebuf, unsigned* __restrict__ counter,
    float* __restrict__ out)
{
    __shared__ __align__(16) ushort_t bufA[16 * 256];
    __shared__ __align__(16) ushort_t bufB[16 * 256];
    __shared__ __align__(16) float h2f[16 * 160];
    __shared__ float ered[MTILE];

    int t = threadIdx.x;
    int lane = t & 63, wv = t >> 6;
    int bid = blockIdx.x;

    int sfound = -1, tile = 0, segbase = 0, na = 0;
    int t0 = 0;
    for (int s = 0; s < NSP; ++s) {
        int beg = seg[s], end = seg[s + 1];
        int n = end - beg;
        int nt = (n + MTILE - 1) >> 4;
        if (sfound < 0 && bid < t0 + nt) {
            sfound = s; tile = bid - t0; segbase = beg;
            int rem = n - tile * MTILE;
            na = rem < MTILE ? rem : MTILE;
        }
        t0 += nt;
    }

    float ssum = 0.f;
    if (sfound >= 0) {
        int s = sfound;
        int row0 = segbase + tile * MTILE;

        float w3v[5];
        {
            const float* w3 = W3 + (size_t)s * 160 + (t & 31);
#pragma unroll
            for (int j = 0; j < 5; ++j) w3v[j] = w3[j * 32];
        }

        // L0 weight fragments issued BEFORE the staging barrier
        short8 wf0[2][4];
        short8 wf1[2][8];
        short8 wf2[2][6];
        short8 wfd[1][1];   // dummy for the last layer
        load_wf<4, 16>(wr0 + (size_t)s * 16 * 4 * 512, wf0, lane, wv);

        // stage AEV rows (bf16, swizzled); rows>=na, cols>=112 zeroed
        if (t < 256) {
            int m = t >> 4, piece = t & 15;
            short8 v = (short8){0,0,0,0,0,0,0,0};
            if (m < na && piece < 14)
                v = *(const short8*)(aevb + (size_t)(row0 + m) * AEVD + piece * 8);
            unsigned addr = (unsigned)(m * 256 + piece * 16) ^ ((unsigned)((m & 7) << 4));
            *(short8*)((char*)bufA + addr) = v;
        }
        __syncthreads();

        compute_layer8<4, 16, 128, 256, false, 8, 12, true>(
            b0 + s * 256, bufA, bufB, nullptr, wf0,
            wr1 + (size_t)s * 12 * 8 * 512, wf1, lane, wv);
        compute_layer8<8, 12, 256, 192, false, 6, 10, true>(
            b1 + s * 192, bufB, bufA, nullptr, wf1,
            wr2 + (size_t)s * 10 * 6 * 512, wf2, lane, wv);
        compute_layer8<6, 10, 192, 160, true, 1, 1, false>(
            b2 + s * 160, bufA, nullptr, h2f, wf2,
            nullptr, wfd, lane, wv);

        // ---- Layer 3: 160 -> 1 per atom (32 lanes per atom, 16 atoms) ----
        {
            int a = t >> 5, l = t & 31;
            float part = 0.f;
#pragma unroll
            for (int j = 0; j < 5; ++j) part = fmaf(h2f[a * 160 + l + j * 32], w3v[j], part);
            for (int off = 16; off; off >>= 1) part += __shfl_down(part, off, 32);
            if (l == 0) ered[a] = part;
        }
        __syncthreads();
        if (t == 0) {
            for (int a = 0; a < na; ++a) ssum += ered[a] + b3[s];
        }
    }

    // completion protocol: last block reduces ebuf in FIXED order (deterministic)
    if (t == 0) {
        ebuf[bid] = ssum;
        __threadfence();
        unsigned old = atomicAdd(counter, 1u);
        if (old == (unsigned)gridDim.x - 1u) {
            __threadfence();
            float tot = 0.f;
            for (int i = 0; i < (int)gridDim.x; ++i) tot += ebuf[i];
            out[0] = tot;
        }
    }
}

extern "C" void kernel_launch(void* const* d_in, const int* in_sizes, int n_in,
                              void* d_out, int out_size, void* d_ws, size_t ws_size,
                              hipStream_t stream)
{
    const int*   species = (const int*)d_in[0];
    const float* coords  = (const float*)d_in[1];
    const float* W0 = (const float*)d_in[2];
    const float* b0 = (const float*)d_in[3];
    const float* W1 = (const float*)d_in[4];
    const float* b1 = (const float*)d_in[5];
    const float* W2 = (const float*)d_in[6];
    const float* b2 = (const float*)d_in[7];
    const float* W3 = (const float*)d_in[8];
    const float* b3 = (const float*)d_in[9];
    float* out = (float*)d_out;

    // Workspace layout: total 2,069,632 B (< 2 MiB)
    char* ws = (char*)d_ws;
    int*      seg     = (int*)(ws);                   // [0, 32)
    unsigned* counter = (unsigned*)(ws + 48);         // [48, 52)
    float*    ebuf    = (float*)(ws + 64);            // 135 f32
    float4*   cxyz    = (float4*)(ws + 1152);         // 2048 float4 (32 KB)
    ushort_t* aevb    = (ushort_t*)(ws + 33920);      // 2048*112 bf16 (448 KB)
    ushort_t* wr0     = (ushort_t*)(ws + 492672);     // 229376 bf16
    ushort_t* wr1     = (ushort_t*)(ws + 951424);     // 344064 bf16
    ushort_t* wr2     = (ushort_t*)(ws + 1639552);    // 215040 bf16

    hipLaunchKernelGGL(sortprep_kernel, dim3(98), dim3(1024), 0, stream,
                       species, coords, seg, cxyz, counter,
                       W0, W1, W2, wr0, wr1, wr2);
    hipLaunchKernelGGL(aev_kernel, dim3(AEV_BLKS), dim3(256), 0, stream,
                       seg, cxyz, aevb);
    hipLaunchKernelGGL(mlp_kernel, dim3(NBLK_MLP), dim3(512), 0, stream,
                       seg, aevb, wr0, wr1, wr2, b0, b1, b2, W3, b3,
                       ebuf, counter, out);
}

// Round 6
// 38.729 us; speedup vs baseline: 1.2588x; 1.0688x over previous
//
#include <hip/hip_runtime.h>
#include <hip/hip_fp16.h>
#include <math.h>

#define N_ATOMS 2048
#define NSP 7
#define AEVD 112      // real radial features; padded to 128 (K-tile) only in LDS
#define MTILE 16      // atoms per MLP block (full 16-row M-tile)
#define NBLK_MLP 135  // max tiles: 2048/16 + 7 slack
#define AEV_TASKS (N_ATOMS * NSP)           // (atom, species) wave-tasks, 16 shells each
#define AEV_BLKS (AEV_TASKS / 4)            // 3584 blocks of 4 waves

typedef __attribute__((ext_vector_type(8))) short short8;
typedef __attribute__((ext_vector_type(4))) float f32x4;
typedef __attribute__((ext_vector_type(2))) float f32x2;
typedef unsigned short ushort_t;

// ---- guaranteed-native transcendentals (single HW instruction) ----
#if !__has_builtin(__builtin_amdgcn_exp2f)
extern "C" __device__ float __ocml_native_exp2_f32(float);
#endif
#if !__has_builtin(__builtin_amdgcn_cosf)
extern "C" __device__ float __ocml_native_cos_f32(float);
#endif
#if !__has_builtin(__builtin_amdgcn_sqrtf)
extern "C" __device__ float __ocml_native_sqrt_f32(float);
#endif

__device__ __forceinline__ float nexp2(float x) {       // 2^x  (v_exp_f32)
#if __has_builtin(__builtin_amdgcn_exp2f)
    return __builtin_amdgcn_exp2f(x);
#else
    return __ocml_native_exp2_f32(x);
#endif
}
__device__ __forceinline__ float ncos_rev(float x) {    // cos(2*pi*x) (v_cos_f32)
#if __has_builtin(__builtin_amdgcn_cosf)
    return __builtin_amdgcn_cosf(x);
#else
    return __ocml_native_cos_f32(x * 6.2831853071795865f);
#endif
}
__device__ __forceinline__ float nsqrt(float x) {       // sqrt(x) (v_sqrt_f32)
#if __has_builtin(__builtin_amdgcn_sqrtf)
    return __builtin_amdgcn_sqrtf(x);
#else
    return __ocml_native_sqrt_f32(x);
#endif
}

// even-shell mus (ladder order; SHFR[2j] = mu_e[j])
__device__ __constant__ float c_mue[8] = {0.9f, 1.43f, 1.96f, 2.49f,
                                          3.02f, 3.55f, 4.08f, 4.61f};

#define CS_LOG2E  (-23.083120654223414f)   // -16*log2(e)
#define CB_LOG2E  ( 46.166241308446828f)   // +32*log2(e)
#define EA_COEF   ( 12.003222740196175f)   // CB_LOG2E * 0.26 (even->odd shell step)
#define EB_COEF   ( 24.468107893476819f)   // CB_LOG2E * 0.53 (even->even shell step)

__device__ __forceinline__ float celu01(float x) {
    return x > 0.f ? x : 0.1f * (nexp2(x * 14.426950f) - 1.f);
}

__device__ __forceinline__ ushort_t f2bf(float v) {   // RNE fp32->bf16
    unsigned u = __float_as_uint(v);
    u += 0x7fffu + ((u >> 16) & 1u);
    return (ushort_t)(u >> 16);
}

__device__ __forceinline__ unsigned pkadd16(unsigned a, unsigned b) {  // v_pk_add_f16
    __half2 x, y;
    __builtin_memcpy(&x, &a, 4);
    __builtin_memcpy(&y, &b, 4);
    __half2 r = __hadd2(x, y);
    unsigned u;
    __builtin_memcpy(&u, &r, 4);
    return u;
}

// ---------------------------------------------------------------------------
// Kernel 1 (fused): block 0 = deterministic counting sort + ladder-constant
// precompute (threads 0..13 -> cvec), 1024 threads (2 atoms/thread,
// two-stage scan, 2-round gather); blocks 1..97 = weight repack fp32->bf16.
// NOTE: repack store offset MUST use the branch-LOCAL fragment index g.
// ---------------------------------------------------------------------------
#define PREP_G0 28672   // 7*16*4*64
#define PREP_G1 43008   // 7*12*8*64
#define PREP_G2 26880   // 7*10*6*64
#define PREP_GT (PREP_G0 + PREP_G1 + PREP_G2)   // 98560 <= 97*1024

__global__ __launch_bounds__(1024) void sortprep_kernel(
    const int* __restrict__ species, const float* __restrict__ coords,
    int* __restrict__ seg, float4* __restrict__ cxyz,
    unsigned* __restrict__ counter, float* __restrict__ cvec,
    const float* __restrict__ W0, const float* __restrict__ W1,
    const float* __restrict__ W2,
    ushort_t* __restrict__ wr0, ushort_t* __restrict__ wr1,
    ushort_t* __restrict__ wr2)
{
    __shared__ int wsum[16][NSP];   // per-wave per-species counts
    __shared__ int wpre[16][NSP];   // inclusive prefix over waves
    __shared__ int sortedL[N_ATOMS];
    int t = threadIdx.x;

    if (blockIdx.x != 0) {
        int g = (blockIdx.x - 1) * 1024 + t;
        if (g < PREP_GT) {
            const float* W; ushort_t* dst; int NT, KS, KREAL, KIN, NOUT;
            if (g < PREP_G0)                 { W = W0; dst = wr0; NT = 16; KS = 4; KREAL = 112; KIN = 1008; NOUT = 256; }
            else if (g < PREP_G0 + PREP_G1)  { g -= PREP_G0; W = W1; dst = wr1; NT = 12; KS = 8; KREAL = 256; KIN = 256; NOUT = 192; }
            else                             { g -= PREP_G0 + PREP_G1; W = W2; dst = wr2; NT = 10; KS = 6; KREAL = 192; KIN = 192; NOUT = 160; }
            int L = g & 63, rest = g >> 6;
            int ks = rest % KS; rest /= KS;
            int nt = rest % NT; int s = rest / NT;
            int n = nt * 16 + (L & 15);
            int k0 = ks * 32 + ((L >> 4) << 3);
            const float* src = W + (size_t)s * KIN * NOUT + n;
            short8 v8;
#pragma unroll
            for (int j = 0; j < 8; ++j) {
                int k = k0 + j;
                float v = (k < KREAL) ? src[(size_t)k * NOUT] : 0.f;
                v8[j] = (short)f2bf(v);
            }
            *(short8*)(dst + (size_t)g * 8) = v8;   // LOCAL g
        }
        return;
    }

    // ---- block 0 extra: ladder constants for the AEV kernel ----
    // cvec[0..5] = cke pairs {lo,hi} x3; cvec[6..13] = cko[0..7]
    if (t < 14) {
        float v;
        if (t < 6) {
            int i = t >> 1;                 // chain step 0..2
            int hi = t & 1;                 // 0 = lo chain, 1 = hi chain
            float b = c_mue[i + (hi ? 4 : 0)];
            float a = c_mue[i + (hi ? 5 : 1)];
            v = nexp2(CS_LOG2E * (a * a - b * b));
        } else {
            int j = t - 6;                  // 0..7
            float me = c_mue[j], mo = me + 0.26f;
            v = nexp2(CS_LOG2E * (mo * mo - me * me));
        }
        cvec[t] = v;
    }

    // ---- block 0: counting sort (1024 threads = 16 waves, 2 atoms/thread) ----
    int lane = t & 63, wv = t >> 6;
    if (t == 0) counter[0] = 0u;

    int s0 = species[2 * t], s1 = species[2 * t + 1];
    int c[NSP], incl[NSP];
#pragma unroll
    for (int s = 0; s < NSP; ++s) c[s] = (s0 == s ? 1 : 0) + (s1 == s ? 1 : 0);
#pragma unroll
    for (int s = 0; s < NSP; ++s) {
        int v = c[s];
        for (int d = 1; d < 64; d <<= 1) {
            int o = __shfl_up(v, d);
            if (lane >= d) v += o;
        }
        incl[s] = v;
        if (lane == 63) wsum[wv][s] = v;
    }
    __syncthreads();

    // cross-wave scan: 112 lanes (2 waves), width-16 shfl scan per species
    if (t < 112) {
        int s = t >> 4;
        int w = t & 15;
        int v = wsum[w][s];
        for (int d = 1; d < 16; d <<= 1) {
            int o = __shfl_up(v, d, 16);
            if ((t & 15) >= d) v += o;
        }
        wpre[w][s] = v;                     // inclusive over waves 0..w
    }
    __syncthreads();

    int bs[NSP];
    int run = 0;
#pragma unroll
    for (int s = 0; s < NSP; ++s) {
        int tot = wpre[15][s];
        int woff = wpre[wv][s] - wsum[wv][s];          // exclusive wave prefix
        bs[s] = run + woff + incl[s] - c[s];           // exclusive lane prefix
        if (t == 0) seg[s] = run;
        run += tot;
    }
    if (t == 0) seg[NSP] = run;

    // stable scatter of this thread's 2 atoms
    {
        int p0 = bs[s0]++; sortedL[p0] = 2 * t;
        int p1 = bs[s1]++; sortedL[p1] = 2 * t + 1;
    }
    __syncthreads();

    for (int p = t; p < N_ATOMS; p += 1024) {
        int j = sortedL[p];
        cxyz[p] = make_float4(coords[3 * j + 0], coords[3 * j + 1],
                              coords[3 * j + 2], 0.f);
    }
}

// ---------------------------------------------------------------------------
// Kernel 2: radial AEV, one wave-task = (atom, species), all 16 shells.
// R6: (a) ladder constants loaded from cvec (wave-uniform scalar loads;
// removes 14 v_exp_f32 from every task's prologue); (b) fold-reduction:
// word count halves at each of the first 3 butterfly stages ("send the
// word you don't keep"), then 3 plain xor stages on the survivor — 34
// instructions vs 96.  Word w ends on lane group jl>>3 == w; lane 8w
// writes shells (2w,2w+1) as one packed dword (8 x 4B, coalesced 32B).
// ---------------------------------------------------------------------------
__global__ __launch_bounds__(256) void aev_kernel(
    const int* __restrict__ seg, const float4* __restrict__ cxyz,
    const float* __restrict__ cvec, ushort_t* __restrict__ aevb)
{
    int t = threadIdx.x;
    int jl = t & 63;
    int gid = blockIdx.x * 4 + (t >> 6);   // 0 .. 14335
    int atom = gid / 7;                    // magic-mul const div
    int s = gid - atom * 7;

    float4 ci = cxyz[atom];
    float xi = ci.x, yi = ci.y, zi = ci.z;
    int pb = seg[s], pe = seg[s + 1];

    // anchor constants (compile-time folded literal arithmetic)
    const float BE_A0 = CB_LOG2E * 0.9f;
    const float GE_A0 = CS_LOG2E * (0.9f * 0.9f);
    const float BE_A1 = CB_LOG2E * 3.02f;
    const float GE_A1 = CS_LOG2E * (3.02f * 3.02f);

    // ladder constants (uniform -> scalar loads; latency overlaps seg/cxyz)
    f32x2 cke0 = (f32x2){cvec[0], cvec[1]};
    f32x2 cke1 = (f32x2){cvec[2], cvec[3]};
    f32x2 cke2 = (f32x2){cvec[4], cvec[5]};
    float cko[8];
#pragma unroll
    for (int j = 0; j < 8; ++j) cko[j] = cvec[6 + j];

    f32x2 accE[4], accO[4];
#pragma unroll
    for (int i = 0; i < 4; ++i) {
        accE[i] = (f32x2){0.f, 0.f};
        accO[i] = (f32x2){0.f, 0.f};
    }

    const float4* pj = cxyz + pb + jl;
    for (int n = pe - pb - jl; n > 0; n -= 64, pj += 64) {
        float4 cj = *pj;                           // L1-resident (32KB total)
        float dx = cj.x - xi, dy = cj.y - yi, dz = cj.z - zi;
        float sq = fmaf(dx, dx, fmaf(dy, dy, dz * dz));
        float d  = nsqrt(sq);
        float dc = fminf(d, 5.2f);                 // clamp: keeps eb/ea finite; fc(5.2)=0
        float fc = fmaf(0.5f, ncos_rev(dc * 0.09615384615f), 0.5f);
        float uc = CS_LOG2E * sq;
        float ea = nexp2(dc * EA_COEF);            // even->odd ratio (shared)
        float fe = ea * fc;
        float ebv = nexp2(dc * EB_COEF);           // even->even ratio (shared)
        f32x2 eb2 = (f32x2){ebv, ebv};
        f32x2 fc2 = (f32x2){fc, fc};
        f32x2 fe2 = (f32x2){fe, fe};
        f32x2 ek0 = eb2 * cke0;
        f32x2 ek1 = eb2 * cke1;
        f32x2 ek2 = eb2 * cke2;
        f32x2 ve = (f32x2){ nexp2(fmaf(dc, BE_A0, uc) + GE_A0),
                            nexp2(fmaf(dc, BE_A1, uc) + GE_A1) };
        accE[0] = ve * fc2 + accE[0];  accO[0] = ve * fe2 + accO[0];
        ve = ve * ek0;
        accE[1] = ve * fc2 + accE[1];  accO[1] = ve * fe2 + accO[1];
        ve = ve * ek1;
        accE[2] = ve * fc2 + accE[2];  accO[2] = ve * fe2 + accO[2];
        ve = ve * ek2;
        accE[3] = ve * fc2 + accE[3];  accO[3] = ve * fe2 + accO[3];
    }

    // subtract the self-pair: exact replica of the in-loop ladder at sq=0
    // (dc=0 -> fc=1, fe=1, eb=1 -> ek=cke; fma with multiplier 1.0 == add)
    if (pb <= atom && atom < pe && ((atom - pb) & 63) == jl) {
        f32x2 ve = (f32x2){ nexp2(GE_A0), nexp2(GE_A1) };
        accE[0] -= ve;  accO[0] -= ve;
        ve = ve * cke0;
        accE[1] -= ve;  accO[1] -= ve;
        ve = ve * cke1;
        accE[2] -= ve;  accO[2] -= ve;
        ve = ve * cke2;
        accE[3] -= ve;  accO[3] -= ve;
    }

    // pack to half2 words: hu[j] = {E[j], O[j]*cko[j]} (shells 2j, 2j+1)
    unsigned hu[8];
#pragma unroll
    for (int j = 0; j < 8; ++j) {
        float E = (j < 4) ? accE[j][0] : accE[j - 4][1];
        float O = ((j < 4) ? accO[j][0] : accO[j - 4][1]) * cko[j];
        __half2 hh = __floats2half2_rn(E, O);
        __builtin_memcpy(&hu[j], &hh, 4);
    }

    // ---- fold-reduction: 34 ops vs 96 for the full butterfly ----
    bool hi5 = (jl & 32) != 0;
#pragma unroll
    for (int j = 0; j < 4; ++j) {                       // xor 32: keep 4 words
        unsigned snd = hi5 ? hu[j] : hu[j + 4];
        unsigned rcv = (unsigned)__shfl_xor((int)snd, 32);
        unsigned kp  = hi5 ? hu[j + 4] : hu[j];
        hu[j] = pkadd16(kp, rcv);
    }
    bool hi4 = (jl & 16) != 0;
#pragma unroll
    for (int j = 0; j < 2; ++j) {                       // xor 16: keep 2 words
        unsigned snd = hi4 ? hu[j] : hu[j + 2];
        unsigned rcv = (unsigned)__shfl_xor((int)snd, 16);
        unsigned kp  = hi4 ? hu[j + 2] : hu[j];
        hu[j] = pkadd16(kp, rcv);
    }
    bool hi3 = (jl & 8) != 0;
    {                                                   // xor 8: keep 1 word
        unsigned snd = hi3 ? hu[0] : hu[1];
        unsigned rcv = (unsigned)__shfl_xor((int)snd, 8);
        unsigned kp  = hi3 ? hu[1] : hu[0];
        hu[0] = pkadd16(kp, rcv);
    }
#pragma unroll
    for (int off = 4; off; off >>= 1)                   // xor 4,2,1
        hu[0] = pkadd16(hu[0], (unsigned)__shfl_xor((int)hu[0], off));

    // word w = (jl>>3)&7 lives on lanes 8w..8w+7; lane 8w writes shells (2w,2w+1)
    if ((jl & 7) == 0) {
        int w = jl >> 3;
        __half2 hv;
        __builtin_memcpy(&hv, &hu[0], 4);
        float2 f = __half22float2(hv);
        unsigned pk = (unsigned)f2bf(f.x) | ((unsigned)f2bf(f.y) << 16);
        *(unsigned*)(aevb + (size_t)atom * AEVD + s * 16 + 2 * w) = pk;
    }
}

// ---------------------------------------------------------------------------
// Kernel 3: MFMA MLP — 512 threads, 8 waves split the N-tiles.  Next-layer
// weight fragments prefetched BEFORE the current layer's MFMAs (L2 latency
// hides under compute); L0 weights issued before the staging sync.
// Peak live wf state = wf1+wf2 = 28 short8 = 112 VGPR — no spill at 256 cap.
// ---------------------------------------------------------------------------

template<int KSTEPS, int NT>
__device__ __forceinline__ void load_wf(const ushort_t* __restrict__ wrep,
                                        short8 (&wf)[(NT + 7) / 8][KSTEPS],
                                        int lane, int wv)
{
    constexpr int MAXNT = (NT + 7) / 8;
    const int myNT = (NT - wv + 7) / 8;
#pragma unroll
    for (int i = 0; i < MAXNT; ++i) {
        if (i < myNT) {
            int nt = wv + i * 8;
            const ushort_t* wb = wrep + ((size_t)nt * KSTEPS) * 512 + lane * 8;
#pragma unroll
            for (int ks = 0; ks < KSTEPS; ++ks)
                wf[i][ks] = *(const short8*)(wb + ks * 512);
        }
    }
}

template<int KSTEPS, int NT, int SIN, int NOUT, bool OUTF32, int NKSTEPS, int NNT, bool PREF>
__device__ __forceinline__ void compute_layer8(
    const float* __restrict__ bias,
    const ushort_t* Ain,                 // LDS bf16 [16][SIN], swizzled
    ushort_t* Aout,                      // LDS bf16 [16][NOUT], swizzled
    float* Fout,                         // LDS fp32 [16][NOUT] (if OUTF32)
    short8 (&wf)[(NT + 7) / 8][KSTEPS],  // preloaded B fragments for THIS layer
    const ushort_t* __restrict__ nwrep,  // next-layer weight base
    short8 (&nwf)[(NNT + 7) / 8][NKSTEPS],
    int lane, int wv)
{
    constexpr int MAXNT = (NT + 7) / 8;
    const int myNT = (NT - wv + 7) / 8;

    // prefetch NEXT layer's B fragments first (global; latency hides under MFMA)
    if constexpr (PREF) {
        load_wf<NKSTEPS, NNT>(nwrep, nwf, lane, wv);
    }

    // A fragments (shared across this wave's N-tiles)
    short8 af[KSTEPS];
    {
        int m = lane & 15;
        int kb = (lane >> 4) << 3;
        unsigned base = (unsigned)(m * (SIN * 2));
        unsigned swz = (unsigned)((m & 7) << 4);
#pragma unroll
        for (int ks = 0; ks < KSTEPS; ++ks) {
            unsigned addr = (base + (unsigned)((ks * 32 + kb) * 2)) ^ swz;
            af[ks] = *(const short8*)((const char*)Ain + addr);
        }
    }
    f32x4 acc[MAXNT];
#pragma unroll
    for (int i = 0; i < MAXNT; ++i) {
        acc[i] = (f32x4){0.f, 0.f, 0.f, 0.f};
        if (i < myNT) {
#pragma unroll
            for (int ks = 0; ks < KSTEPS; ++ks)
                acc[i] = __builtin_amdgcn_mfma_f32_16x16x32_bf16(af[ks], wf[i][ks], acc[i], 0, 0, 0);
        }
    }
    // epilogue: bias + celu; D layout: n = lane&15, m = (lane>>4)*4 + r
#pragma unroll
    for (int i = 0; i < MAXNT; ++i) {
        if (i < myNT) {
            int nt = wv + i * 8;
            int n = nt * 16 + (lane & 15);
            float bb = bias[n];
#pragma unroll
            for (int r = 0; r < 4; ++r) {
                int m = ((lane >> 4) << 2) + r;
                float v = celu01(acc[i][r] + bb);
                if (OUTF32) {
                    Fout[m * NOUT + n] = v;
                } else {
                    unsigned addr = (unsigned)(m * (NOUT * 2) + n * 2) ^ ((unsigned)((m & 7) << 4));
                    *(ushort_t*)((char*)Aout + addr) = f2bf(v);
                }
            }
        }
    }
    __syncthreads();
}

__global__ __launch_bounds__(512, 1) void mlp_kernel(
    const int* __restrict__ seg, const ushort_t* __restrict__ aevb,
    const ushort_t* __restrict__ wr0, const ushort_t* __restrict__ wr1,
    const ushort_t* __restrict__ wr2,
    const float* __restrict__ b0, const float* __restrict__ b1,
    const float* __restrict__ b2,
    const float* __restrict__ W3, const float* __restrict__ b3,
    float* __restrict__ ebuf, unsigned* __restrict__ counter,
    float* __restrict__ out)
{
    __shared__ __align__(16) ushort_t bufA[16 * 256];
    __shared__ __align__(16) ushort_t bufB[16 * 256];
    __shared__ __align__(16) float h2f[16 * 160];
    __shared__ float ered[MTILE];

    int t = threadIdx.x;
    int lane = t & 63, wv = t >> 6;
    int bid = blockIdx.x;

    int sfound = -1, tile = 0, segbase = 0, na = 0;
    int t0 = 0;
    for (int s = 0; s < NSP; ++s) {
        int beg = seg[s], end = seg[s + 1];
        int n = end - beg;
        int nt = (n + MTILE - 1) >> 4;
        if (sfound < 0 && bid < t0 + nt) {
            sfound = s; tile = bid - t0; segbase = beg;
            int rem = n - tile * MTILE;
            na = rem < MTILE ? rem : MTILE;
        }
        t0 += nt;
    }

    float ssum = 0.f;
    if (sfound >= 0) {
        int s = sfound;
        int row0 = segbase + tile * MTILE;

        float w3v[5];
        {
            const float* w3 = W3 + (size_t)s * 160 + (t & 31);
#pragma unroll
            for (int j = 0; j < 5; ++j) w3v[j] = w3[j * 32];
        }

        // L0 weight fragments issued BEFORE the staging barrier
        short8 wf0[2][4];
        short8 wf1[2][8];
        short8 wf2[2][6];
        short8 wfd[1][1];   // dummy for the last layer
        load_wf<4, 16>(wr0 + (size_t)s * 16 * 4 * 512, wf0, lane, wv);

        // stage AEV rows (bf16, swizzled); rows>=na, cols>=112 zeroed
        if (t < 256) {
            int m = t >> 4, piece = t & 15;
            short8 v = (short8){0,0,0,0,0,0,0,0};
            if (m < na && piece < 14)
                v = *(const short8*)(aevb + (size_t)(row0 + m) * AEVD + piece * 8);
            unsigned addr = (unsigned)(m * 256 + piece * 16) ^ ((unsigned)((m & 7) << 4));
            *(short8*)((char*)bufA + addr) = v;
        }
        __syncthreads();

        compute_layer8<4, 16, 128, 256, false, 8, 12, true>(
            b0 + s * 256, bufA, bufB, nullptr, wf0,
            wr1 + (size_t)s * 12 * 8 * 512, wf1, lane, wv);
        compute_layer8<8, 12, 256, 192, false, 6, 10, true>(
            b1 + s * 192, bufB, bufA, nullptr, wf1,
            wr2 + (size_t)s * 10 * 6 * 512, wf2, lane, wv);
        compute_layer8<6, 10, 192, 160, true, 1, 1, false>(
            b2 + s * 160, bufA, nullptr, h2f, wf2,
            nullptr, wfd, lane, wv);

        // ---- Layer 3: 160 -> 1 per atom (32 lanes per atom, 16 atoms) ----
        {
            int a = t >> 5, l = t & 31;
            float part = 0.f;
#pragma unroll
            for (int j = 0; j < 5; ++j) part = fmaf(h2f[a * 160 + l + j * 32], w3v[j], part);
            for (int off = 16; off; off >>= 1) part += __shfl_down(part, off, 32);
            if (l == 0) ered[a] = part;
        }
        __syncthreads();
        if (t == 0) {
            for (int a = 0; a < na; ++a) ssum += ered[a] + b3[s];
        }
    }

    // completion protocol: last block reduces ebuf in FIXED order (deterministic)
    if (t == 0) {
        ebuf[bid] = ssum;
        __threadfence();
        unsigned old = atomicAdd(counter, 1u);
        if (old == (unsigned)gridDim.x - 1u) {
            __threadfence();
            float tot = 0.f;
            for (int i = 0; i < (int)gridDim.x; ++i) tot += ebuf[i];
            out[0] = tot;
        }
    }
}

extern "C" void kernel_launch(void* const* d_in, const int* in_sizes, int n_in,
                              void* d_out, int out_size, void* d_ws, size_t ws_size,
                              hipStream_t stream)
{
    const int*   species = (const int*)d_in[0];
    const float* coords  = (const float*)d_in[1];
    const float* W0 = (const float*)d_in[2];
    const float* b0 = (const float*)d_in[3];
    const float* W1 = (const float*)d_in[4];
    const float* b1 = (const float*)d_in[5];
    const float* W2 = (const float*)d_in[6];
    const float* b2 = (const float*)d_in[7];
    const float* W3 = (const float*)d_in[8];
    const float* b3 = (const float*)d_in[9];
    float* out = (float*)d_out;

    // Workspace layout: total 2,069,632 B (< 2 MiB)
    char* ws = (char*)d_ws;
    int*      seg     = (int*)(ws);                   // [0, 32)
    unsigned* counter = (unsigned*)(ws + 48);         // [48, 52)
    float*    ebuf    = (float*)(ws + 64);            // 135 f32 -> ends 604
    float*    cvec    = (float*)(ws + 640);           // 14 f32 ladder constants
    float4*   cxyz    = (float4*)(ws + 1152);         // 2048 float4 (32 KB)
    ushort_t* aevb    = (ushort_t*)(ws + 33920);      // 2048*112 bf16 (448 KB)
    ushort_t* wr0     = (ushort_t*)(ws + 492672);     // 229376 bf16
    ushort_t* wr1     = (ushort_t*)(ws + 951424);     // 344064 bf16
    ushort_t* wr2     = (ushort_t*)(ws + 1639552);    // 215040 bf16

    hipLaunchKernelGGL(sortprep_kernel, dim3(98), dim3(1024), 0, stream,
                       species, coords, seg, cxyz, counter, cvec,
                       W0, W1, W2, wr0, wr1, wr2);
    hipLaunchKernelGGL(aev_kernel, dim3(AEV_BLKS), dim3(256), 0, stream,
                       seg, cxyz, cvec, aevb);
    hipLaunchKernelGGL(mlp_kernel, dim3(NBLK_MLP), dim3(512), 0, stream,
                       seg, aevb, wr0, wr1, wr2, b0, b1, b2, W3, b3,
                       ebuf, counter, out);
}

// Round 7
// 32.027 us; speedup vs baseline: 1.5222x; 1.2092x over previous
//
#include <hip/hip_runtime.h>
#include <hip/hip_fp16.h>
#include <math.h>

#define N_ATOMS 2048
#define NSP 7
#define AEVD 112      // real radial features; padded to 128 (K-tile) only in LDS
#define MTILE 16      // atoms per MLP block (full 16-row M-tile)
#define NBLK_MLP 135  // max tiles: 2048/16 + 7 slack
#define AEV_TASKS (N_ATOMS * NSP)           // (atom, species) wave-tasks, 16 shells each
#define AEV_BLKS (AEV_TASKS / 4)            // 3584 blocks of 4 waves

typedef __attribute__((ext_vector_type(8))) short short8;
typedef __attribute__((ext_vector_type(4))) float f32x4;
typedef __attribute__((ext_vector_type(2))) float f32x2;
typedef unsigned short ushort_t;

// ---- guaranteed-native transcendentals (single HW instruction) ----
#if !__has_builtin(__builtin_amdgcn_exp2f)
extern "C" __device__ float __ocml_native_exp2_f32(float);
#endif
#if !__has_builtin(__builtin_amdgcn_cosf)
extern "C" __device__ float __ocml_native_cos_f32(float);
#endif
#if !__has_builtin(__builtin_amdgcn_sqrtf)
extern "C" __device__ float __ocml_native_sqrt_f32(float);
#endif

__device__ __forceinline__ float nexp2(float x) {       // 2^x  (v_exp_f32)
#if __has_builtin(__builtin_amdgcn_exp2f)
    return __builtin_amdgcn_exp2f(x);
#else
    return __ocml_native_exp2_f32(x);
#endif
}
__device__ __forceinline__ float ncos_rev(float x) {    // cos(2*pi*x) (v_cos_f32)
#if __has_builtin(__builtin_amdgcn_cosf)
    return __builtin_amdgcn_cosf(x);
#else
    return __ocml_native_cos_f32(x * 6.2831853071795865f);
#endif
}
__device__ __forceinline__ float nsqrt(float x) {       // sqrt(x) (v_sqrt_f32)
#if __has_builtin(__builtin_amdgcn_sqrtf)
    return __builtin_amdgcn_sqrtf(x);
#else
    return __ocml_native_sqrt_f32(x);
#endif
}

// even-shell mus (ladder order; SHFR[2j] = mu_e[j])
__device__ __constant__ float c_mue[8] = {0.9f, 1.43f, 1.96f, 2.49f,
                                          3.02f, 3.55f, 4.08f, 4.61f};

#define CS_LOG2E  (-23.083120654223414f)   // -16*log2(e)
#define CB_LOG2E  ( 46.166241308446828f)   // +32*log2(e)
#define EA_COEF   ( 12.003222740196175f)   // CB_LOG2E * 0.26 (even->odd shell step)
#define EB_COEF   ( 24.468107893476819f)   // CB_LOG2E * 0.53 (even->even shell step)

__device__ __forceinline__ float celu01(float x) {
    return x > 0.f ? x : 0.1f * (nexp2(x * 14.426950f) - 1.f);
}

__device__ __forceinline__ ushort_t f2bf(float v) {   // RNE fp32->bf16
    unsigned u = __float_as_uint(v);
    u += 0x7fffu + ((u >> 16) & 1u);
    return (ushort_t)(u >> 16);
}

__device__ __forceinline__ unsigned pkadd16(unsigned a, unsigned b) {  // v_pk_add_f16
    __half2 x, y;
    __builtin_memcpy(&x, &a, 4);
    __builtin_memcpy(&y, &b, 4);
    __half2 r = __hadd2(x, y);
    unsigned u;
    __builtin_memcpy(&u, &r, 4);
    return u;
}

// ---------------------------------------------------------------------------
// Kernel 1 (fused): block 0 = deterministic counting sort + ladder-constant
// precompute (threads 0..13 -> cvec); R7: coords staged to LDS coalesced
// (overlaps scan math), gather reads LDS instead of uncoalesced HBM.
// Blocks 1..97 = weight repack fp32->bf16.
// NOTE: repack store offset MUST use the branch-LOCAL fragment index g.
// ---------------------------------------------------------------------------
#define PREP_G0 28672   // 7*16*4*64
#define PREP_G1 43008   // 7*12*8*64
#define PREP_G2 26880   // 7*10*6*64
#define PREP_GT (PREP_G0 + PREP_G1 + PREP_G2)   // 98560 <= 97*1024

__global__ __launch_bounds__(1024) void sortprep_kernel(
    const int* __restrict__ species, const float* __restrict__ coords,
    int* __restrict__ seg, float4* __restrict__ cxyz,
    unsigned* __restrict__ counter, float* __restrict__ cvec,
    const float* __restrict__ W0, const float* __restrict__ W1,
    const float* __restrict__ W2,
    ushort_t* __restrict__ wr0, ushort_t* __restrict__ wr1,
    ushort_t* __restrict__ wr2)
{
    __shared__ int wsum[16][NSP];   // per-wave per-species counts
    __shared__ int wpre[16][NSP];   // inclusive prefix over waves
    __shared__ int sortedL[N_ATOMS];
    __shared__ float cloc[3 * N_ATOMS];   // 24 KB staged coords
    int t = threadIdx.x;

    if (blockIdx.x != 0) {
        int g = (blockIdx.x - 1) * 1024 + t;
        if (g < PREP_GT) {
            const float* W; ushort_t* dst; int NT, KS, KREAL, KIN, NOUT;
            if (g < PREP_G0)                 { W = W0; dst = wr0; NT = 16; KS = 4; KREAL = 112; KIN = 1008; NOUT = 256; }
            else if (g < PREP_G0 + PREP_G1)  { g -= PREP_G0; W = W1; dst = wr1; NT = 12; KS = 8; KREAL = 256; KIN = 256; NOUT = 192; }
            else                             { g -= PREP_G0 + PREP_G1; W = W2; dst = wr2; NT = 10; KS = 6; KREAL = 192; KIN = 192; NOUT = 160; }
            int L = g & 63, rest = g >> 6;
            int ks = rest % KS; rest /= KS;
            int nt = rest % NT; int s = rest / NT;
            int n = nt * 16 + (L & 15);
            int k0 = ks * 32 + ((L >> 4) << 3);
            const float* src = W + (size_t)s * KIN * NOUT + n;
            short8 v8;
#pragma unroll
            for (int j = 0; j < 8; ++j) {
                int k = k0 + j;
                float v = (k < KREAL) ? src[(size_t)k * NOUT] : 0.f;
                v8[j] = (short)f2bf(v);
            }
            *(short8*)(dst + (size_t)g * 8) = v8;   // LOCAL g
        }
        return;
    }

    // ---- block 0: coalesced coords -> LDS (latency hides under the scans) ----
#pragma unroll
    for (int i = 0; i < 6; ++i) cloc[t + i * 1024] = coords[t + i * 1024];

    // ---- block 0 extra: ladder constants for the AEV kernel ----
    // cvec[0..5] = cke pairs {lo,hi} x3; cvec[6..13] = cko[0..7]
    if (t < 14) {
        float v;
        if (t < 6) {
            int i = t >> 1;                 // chain step 0..2
            int hi = t & 1;                 // 0 = lo chain, 1 = hi chain
            float b = c_mue[i + (hi ? 4 : 0)];
            float a = c_mue[i + (hi ? 5 : 1)];
            v = nexp2(CS_LOG2E * (a * a - b * b));
        } else {
            int j = t - 6;                  // 0..7
            float me = c_mue[j], mo = me + 0.26f;
            v = nexp2(CS_LOG2E * (mo * mo - me * me));
        }
        cvec[t] = v;
    }

    // ---- counting sort (1024 threads = 16 waves, 2 atoms/thread) ----
    int lane = t & 63, wv = t >> 6;
    if (t == 0) counter[0] = 0u;

    int s0 = species[2 * t], s1 = species[2 * t + 1];
    int c[NSP], incl[NSP];
#pragma unroll
    for (int s = 0; s < NSP; ++s) c[s] = (s0 == s ? 1 : 0) + (s1 == s ? 1 : 0);
#pragma unroll
    for (int s = 0; s < NSP; ++s) {
        int v = c[s];
        for (int d = 1; d < 64; d <<= 1) {
            int o = __shfl_up(v, d);
            if (lane >= d) v += o;
        }
        incl[s] = v;
        if (lane == 63) wsum[wv][s] = v;
    }
    __syncthreads();

    // cross-wave scan: 112 lanes (2 waves), width-16 shfl scan per species
    if (t < 112) {
        int s = t >> 4;
        int w = t & 15;
        int v = wsum[w][s];
        for (int d = 1; d < 16; d <<= 1) {
            int o = __shfl_up(v, d, 16);
            if ((t & 15) >= d) v += o;
        }
        wpre[w][s] = v;                     // inclusive over waves 0..w
    }
    __syncthreads();

    int bs[NSP];
    int run = 0;
#pragma unroll
    for (int s = 0; s < NSP; ++s) {
        int tot = wpre[15][s];
        int woff = wpre[wv][s] - wsum[wv][s];          // exclusive wave prefix
        bs[s] = run + woff + incl[s] - c[s];           // exclusive lane prefix
        if (t == 0) seg[s] = run;
        run += tot;
    }
    if (t == 0) seg[NSP] = run;

    // stable scatter of this thread's 2 atoms
    {
        int p0 = bs[s0]++; sortedL[p0] = 2 * t;
        int p1 = bs[s1]++; sortedL[p1] = 2 * t + 1;
    }
    __syncthreads();

    for (int p = t; p < N_ATOMS; p += 1024) {
        int j = sortedL[p];
        cxyz[p] = make_float4(cloc[3 * j + 0], cloc[3 * j + 1],
                              cloc[3 * j + 2], 0.f);
    }
}

// ---------------------------------------------------------------------------
// Kernel 2: radial AEV, one wave-task = (atom, species), all 16 shells.
// Ladder constants from cvec (wave-uniform scalar loads); fold-reduction
// (34 ops); packed-f32 two-anchor ladder.  (unchanged — control)
// ---------------------------------------------------------------------------
__global__ __launch_bounds__(256) void aev_kernel(
    const int* __restrict__ seg, const float4* __restrict__ cxyz,
    const float* __restrict__ cvec, ushort_t* __restrict__ aevb)
{
    int t = threadIdx.x;
    int jl = t & 63;
    int gid = blockIdx.x * 4 + (t >> 6);   // 0 .. 14335
    int atom = gid / 7;                    // magic-mul const div
    int s = gid - atom * 7;

    float4 ci = cxyz[atom];
    float xi = ci.x, yi = ci.y, zi = ci.z;
    int pb = seg[s], pe = seg[s + 1];

    // anchor constants (compile-time folded literal arithmetic)
    const float BE_A0 = CB_LOG2E * 0.9f;
    const float GE_A0 = CS_LOG2E * (0.9f * 0.9f);
    const float BE_A1 = CB_LOG2E * 3.02f;
    const float GE_A1 = CS_LOG2E * (3.02f * 3.02f);

    // ladder constants (uniform -> scalar loads; latency overlaps seg/cxyz)
    f32x2 cke0 = (f32x2){cvec[0], cvec[1]};
    f32x2 cke1 = (f32x2){cvec[2], cvec[3]};
    f32x2 cke2 = (f32x2){cvec[4], cvec[5]};
    float cko[8];
#pragma unroll
    for (int j = 0; j < 8; ++j) cko[j] = cvec[6 + j];

    f32x2 accE[4], accO[4];
#pragma unroll
    for (int i = 0; i < 4; ++i) {
        accE[i] = (f32x2){0.f, 0.f};
        accO[i] = (f32x2){0.f, 0.f};
    }

    const float4* pj = cxyz + pb + jl;
    for (int n = pe - pb - jl; n > 0; n -= 64, pj += 64) {
        float4 cj = *pj;                           // L1-resident (32KB total)
        float dx = cj.x - xi, dy = cj.y - yi, dz = cj.z - zi;
        float sq = fmaf(dx, dx, fmaf(dy, dy, dz * dz));
        float d  = nsqrt(sq);
        float dc = fminf(d, 5.2f);                 // clamp: keeps eb/ea finite; fc(5.2)=0
        float fc = fmaf(0.5f, ncos_rev(dc * 0.09615384615f), 0.5f);
        float uc = CS_LOG2E * sq;
        float ea = nexp2(dc * EA_COEF);            // even->odd ratio (shared)
        float fe = ea * fc;
        float ebv = nexp2(dc * EB_COEF);           // even->even ratio (shared)
        f32x2 eb2 = (f32x2){ebv, ebv};
        f32x2 fc2 = (f32x2){fc, fc};
        f32x2 fe2 = (f32x2){fe, fe};
        f32x2 ek0 = eb2 * cke0;
        f32x2 ek1 = eb2 * cke1;
        f32x2 ek2 = eb2 * cke2;
        f32x2 ve = (f32x2){ nexp2(fmaf(dc, BE_A0, uc) + GE_A0),
                            nexp2(fmaf(dc, BE_A1, uc) + GE_A1) };
        accE[0] = ve * fc2 + accE[0];  accO[0] = ve * fe2 + accO[0];
        ve = ve * ek0;
        accE[1] = ve * fc2 + accE[1];  accO[1] = ve * fe2 + accO[1];
        ve = ve * ek1;
        accE[2] = ve * fc2 + accE[2];  accO[2] = ve * fe2 + accO[2];
        ve = ve * ek2;
        accE[3] = ve * fc2 + accE[3];  accO[3] = ve * fe2 + accO[3];
    }

    // subtract the self-pair: exact replica of the in-loop ladder at sq=0
    // (dc=0 -> fc=1, fe=1, eb=1 -> ek=cke; fma with multiplier 1.0 == add)
    if (pb <= atom && atom < pe && ((atom - pb) & 63) == jl) {
        f32x2 ve = (f32x2){ nexp2(GE_A0), nexp2(GE_A1) };
        accE[0] -= ve;  accO[0] -= ve;
        ve = ve * cke0;
        accE[1] -= ve;  accO[1] -= ve;
        ve = ve * cke1;
        accE[2] -= ve;  accO[2] -= ve;
        ve = ve * cke2;
        accE[3] -= ve;  accO[3] -= ve;
    }

    // pack to half2 words: hu[j] = {E[j], O[j]*cko[j]} (shells 2j, 2j+1)
    unsigned hu[8];
#pragma unroll
    for (int j = 0; j < 8; ++j) {
        float E = (j < 4) ? accE[j][0] : accE[j - 4][1];
        float O = ((j < 4) ? accO[j][0] : accO[j - 4][1]) * cko[j];
        __half2 hh = __floats2half2_rn(E, O);
        __builtin_memcpy(&hu[j], &hh, 4);
    }

    // ---- fold-reduction: 34 ops vs 96 for the full butterfly ----
    bool hi5 = (jl & 32) != 0;
#pragma unroll
    for (int j = 0; j < 4; ++j) {                       // xor 32: keep 4 words
        unsigned snd = hi5 ? hu[j] : hu[j + 4];
        unsigned rcv = (unsigned)__shfl_xor((int)snd, 32);
        unsigned kp  = hi5 ? hu[j + 4] : hu[j];
        hu[j] = pkadd16(kp, rcv);
    }
    bool hi4 = (jl & 16) != 0;
#pragma unroll
    for (int j = 0; j < 2; ++j) {                       // xor 16: keep 2 words
        unsigned snd = hi4 ? hu[j] : hu[j + 2];
        unsigned rcv = (unsigned)__shfl_xor((int)snd, 16);
        unsigned kp  = hi4 ? hu[j + 2] : hu[j];
        hu[j] = pkadd16(kp, rcv);
    }
    bool hi3 = (jl & 8) != 0;
    {                                                   // xor 8: keep 1 word
        unsigned snd = hi3 ? hu[0] : hu[1];
        unsigned rcv = (unsigned)__shfl_xor((int)snd, 8);
        unsigned kp  = hi3 ? hu[1] : hu[0];
        hu[0] = pkadd16(kp, rcv);
    }
#pragma unroll
    for (int off = 4; off; off >>= 1)                   // xor 4,2,1
        hu[0] = pkadd16(hu[0], (unsigned)__shfl_xor((int)hu[0], off));

    // word w = (jl>>3)&7 lives on lanes 8w..8w+7; lane 8w writes shells (2w,2w+1)
    if ((jl & 7) == 0) {
        int w = jl >> 3;
        __half2 hv;
        __builtin_memcpy(&hv, &hu[0], 4);
        float2 f = __half22float2(hv);
        unsigned pk = (unsigned)f2bf(f.x) | ((unsigned)f2bf(f.y) << 16);
        *(unsigned*)(aevb + (size_t)atom * AEVD + s * 16 + 2 * w) = pk;
    }
}

// ---------------------------------------------------------------------------
// Kernel 3: MFMA MLP — 512 threads, 8 waves split the N-tiles.  Next-layer
// weight fragments prefetched BEFORE the current layer's MFMAs; L0 weights
// issued before the staging sync.  R7: ered-sum and the final 135-element
// ebuf reduction parallelized (were serial t0 loops on the critical tail).
// ---------------------------------------------------------------------------

template<int KSTEPS, int NT>
__device__ __forceinline__ void load_wf(const ushort_t* __restrict__ wrep,
                                        short8 (&wf)[(NT + 7) / 8][KSTEPS],
                                        int lane, int wv)
{
    constexpr int MAXNT = (NT + 7) / 8;
    const int myNT = (NT - wv + 7) / 8;
#pragma unroll
    for (int i = 0; i < MAXNT; ++i) {
        if (i < myNT) {
            int nt = wv + i * 8;
            const ushort_t* wb = wrep + ((size_t)nt * KSTEPS) * 512 + lane * 8;
#pragma unroll
            for (int ks = 0; ks < KSTEPS; ++ks)
                wf[i][ks] = *(const short8*)(wb + ks * 512);
        }
    }
}

template<int KSTEPS, int NT, int SIN, int NOUT, bool OUTF32, int NKSTEPS, int NNT, bool PREF>
__device__ __forceinline__ void compute_layer8(
    const float* __restrict__ bias,
    const ushort_t* Ain,                 // LDS bf16 [16][SIN], swizzled
    ushort_t* Aout,                      // LDS bf16 [16][NOUT], swizzled
    float* Fout,                         // LDS fp32 [16][NOUT] (if OUTF32)
    short8 (&wf)[(NT + 7) / 8][KSTEPS],  // preloaded B fragments for THIS layer
    const ushort_t* __restrict__ nwrep,  // next-layer weight base
    short8 (&nwf)[(NNT + 7) / 8][NKSTEPS],
    int lane, int wv)
{
    constexpr int MAXNT = (NT + 7) / 8;
    const int myNT = (NT - wv + 7) / 8;

    // prefetch NEXT layer's B fragments first (global; latency hides under MFMA)
    if constexpr (PREF) {
        load_wf<NKSTEPS, NNT>(nwrep, nwf, lane, wv);
    }

    // A fragments (shared across this wave's N-tiles)
    short8 af[KSTEPS];
    {
        int m = lane & 15;
        int kb = (lane >> 4) << 3;
        unsigned base = (unsigned)(m * (SIN * 2));
        unsigned swz = (unsigned)((m & 7) << 4);
#pragma unroll
        for (int ks = 0; ks < KSTEPS; ++ks) {
            unsigned addr = (base + (unsigned)((ks * 32 + kb) * 2)) ^ swz;
            af[ks] = *(const short8*)((const char*)Ain + addr);
        }
    }
    f32x4 acc[MAXNT];
#pragma unroll
    for (int i = 0; i < MAXNT; ++i) {
        acc[i] = (f32x4){0.f, 0.f, 0.f, 0.f};
        if (i < myNT) {
#pragma unroll
            for (int ks = 0; ks < KSTEPS; ++ks)
                acc[i] = __builtin_amdgcn_mfma_f32_16x16x32_bf16(af[ks], wf[i][ks], acc[i], 0, 0, 0);
        }
    }
    // epilogue: bias + celu; D layout: n = lane&15, m = (lane>>4)*4 + r
#pragma unroll
    for (int i = 0; i < MAXNT; ++i) {
        if (i < myNT) {
            int nt = wv + i * 8;
            int n = nt * 16 + (lane & 15);
            float bb = bias[n];
#pragma unroll
            for (int r = 0; r < 4; ++r) {
                int m = ((lane >> 4) << 2) + r;
                float v = celu01(acc[i][r] + bb);
                if (OUTF32) {
                    Fout[m * NOUT + n] = v;
                } else {
                    unsigned addr = (unsigned)(m * (NOUT * 2) + n * 2) ^ ((unsigned)((m & 7) << 4));
                    *(ushort_t*)((char*)Aout + addr) = f2bf(v);
                }
            }
        }
    }
    __syncthreads();
}

__global__ __launch_bounds__(512, 1) void mlp_kernel(
    const int* __restrict__ seg, const ushort_t* __restrict__ aevb,
    const ushort_t* __restrict__ wr0, const ushort_t* __restrict__ wr1,
    const ushort_t* __restrict__ wr2,
    const float* __restrict__ b0, const float* __restrict__ b1,
    const float* __restrict__ b2,
    const float* __restrict__ W3, const float* __restrict__ b3,
    float* __restrict__ ebuf, unsigned* __restrict__ counter,
    float* __restrict__ out)
{
    __shared__ __align__(16) ushort_t bufA[16 * 256];
    __shared__ __align__(16) ushort_t bufB[16 * 256];
    __shared__ __align__(16) float h2f[16 * 160];
    __shared__ float ered[MTILE];
    __shared__ float wred[8];
    __shared__ int islast;

    int t = threadIdx.x;
    int lane = t & 63, wv = t >> 6;
    int bid = blockIdx.x;

    int sfound = -1, tile = 0, segbase = 0, na = 0;
    int t0 = 0;
    for (int s = 0; s < NSP; ++s) {
        int beg = seg[s], end = seg[s + 1];
        int n = end - beg;
        int nt = (n + MTILE - 1) >> 4;
        if (sfound < 0 && bid < t0 + nt) {
            sfound = s; tile = bid - t0; segbase = beg;
            int rem = n - tile * MTILE;
            na = rem < MTILE ? rem : MTILE;
        }
        t0 += nt;
    }

    float ssum = 0.f;
    if (sfound >= 0) {
        int s = sfound;
        int row0 = segbase + tile * MTILE;

        float w3v[5];
        {
            const float* w3 = W3 + (size_t)s * 160 + (t & 31);
#pragma unroll
            for (int j = 0; j < 5; ++j) w3v[j] = w3[j * 32];
        }

        // L0 weight fragments issued BEFORE the staging barrier
        short8 wf0[2][4];
        short8 wf1[2][8];
        short8 wf2[2][6];
        short8 wfd[1][1];   // dummy for the last layer
        load_wf<4, 16>(wr0 + (size_t)s * 16 * 4 * 512, wf0, lane, wv);

        // stage AEV rows (bf16, swizzled); rows>=na, cols>=112 zeroed
        if (t < 256) {
            int m = t >> 4, piece = t & 15;
            short8 v = (short8){0,0,0,0,0,0,0,0};
            if (m < na && piece < 14)
                v = *(const short8*)(aevb + (size_t)(row0 + m) * AEVD + piece * 8);
            unsigned addr = (unsigned)(m * 256 + piece * 16) ^ ((unsigned)((m & 7) << 4));
            *(short8*)((char*)bufA + addr) = v;
        }
        __syncthreads();

        compute_layer8<4, 16, 128, 256, false, 8, 12, true>(
            b0 + s * 256, bufA, bufB, nullptr, wf0,
            wr1 + (size_t)s * 12 * 8 * 512, wf1, lane, wv);
        compute_layer8<8, 12, 256, 192, false, 6, 10, true>(
            b1 + s * 192, bufB, bufA, nullptr, wf1,
            wr2 + (size_t)s * 10 * 6 * 512, wf2, lane, wv);
        compute_layer8<6, 10, 192, 160, true, 1, 1, false>(
            b2 + s * 160, bufA, nullptr, h2f, wf2,
            nullptr, wfd, lane, wv);

        // ---- Layer 3: 160 -> 1 per atom (32 lanes per atom, 16 atoms) ----
        {
            int a = t >> 5, l = t & 31;
            float part = 0.f;
#pragma unroll
            for (int j = 0; j < 5; ++j) part = fmaf(h2f[a * 160 + l + j * 32], w3v[j], part);
            for (int off = 16; off; off >>= 1) part += __shfl_down(part, off, 32);
            if (l == 0) ered[a] = part;
        }
        __syncthreads();
        // parallel ered sum (width-16 shuffle tree; deterministic fixed order)
        if (t < 16) {
            float v = (t < na) ? ered[t] : 0.f;
#pragma unroll
            for (int off = 8; off; off >>= 1) v += __shfl_down(v, off, 16);
            if (t == 0) ssum = v + (float)na * b3[s];
        }
    }

    // completion protocol: last block reduces ebuf in PARALLEL (fixed tree,
    // deterministic); islast broadcast via LDS + barrier.
    if (t == 0) {
        ebuf[bid] = ssum;
        __threadfence();
        unsigned old = atomicAdd(counter, 1u);
        islast = (old == (unsigned)gridDim.x - 1u) ? 1 : 0;
    }
    __syncthreads();
    if (islast) {
        __threadfence();
        float v = (t < NBLK_MLP) ? ebuf[t] : 0.f;
#pragma unroll
        for (int off = 32; off; off >>= 1) v += __shfl_down(v, off);
        if (lane == 0) wred[wv] = v;
        __syncthreads();
        if (t == 0) {
            float tot = 0.f;
#pragma unroll
            for (int i = 0; i < 8; ++i) tot += wred[i];
            out[0] = tot;
        }
    }
}

extern "C" void kernel_launch(void* const* d_in, const int* in_sizes, int n_in,
                              void* d_out, int out_size, void* d_ws, size_t ws_size,
                              hipStream_t stream)
{
    const int*   species = (const int*)d_in[0];
    const float* coords  = (const float*)d_in[1];
    const float* W0 = (const float*)d_in[2];
    const float* b0 = (const float*)d_in[3];
    const float* W1 = (const float*)d_in[4];
    const float* b1 = (const float*)d_in[5];
    const float* W2 = (const float*)d_in[6];
    const float* b2 = (const float*)d_in[7];
    const float* W3 = (const float*)d_in[8];
    const float* b3 = (const float*)d_in[9];
    float* out = (float*)d_out;

    // Workspace layout: total 2,069,632 B (< 2 MiB)
    char* ws = (char*)d_ws;
    int*      seg     = (int*)(ws);                   // [0, 32)
    unsigned* counter = (unsigned*)(ws + 48);         // [48, 52)
    float*    ebuf    = (float*)(ws + 64);            // 135 f32 -> ends 604
    float*    cvec    = (float*)(ws + 640);           // 14 f32 ladder constants
    float4*   cxyz    = (float4*)(ws + 1152);         // 2048 float4 (32 KB)
    ushort_t* aevb    = (ushort_t*)(ws + 33920);      // 2048*112 bf16 (448 KB)
    ushort_t* wr0     = (ushort_t*)(ws + 492672);     // 229376 bf16
    ushort_t* wr1     = (ushort_t*)(ws + 951424);     // 344064 bf16
    ushort_t* wr2     = (ushort_t*)(ws + 1639552);    // 215040 bf16

    hipLaunchKernelGGL(sortprep_kernel, dim3(98), dim3(1024), 0, stream,
                       species, coords, seg, cxyz, counter, cvec,
                       W0, W1, W2, wr0, wr1, wr2);
    hipLaunchKernelGGL(aev_kernel, dim3(AEV_BLKS), dim3(256), 0, stream,
                       seg, cxyz, cvec, aevb);
    hipLaunchKernelGGL(mlp_kernel, dim3(NBLK_MLP), dim3(512), 0, stream,
                       seg, aevb, wr0, wr1, wr2, b0, b1, b2, W3, b3,
                       ebuf, counter, out);
}